// Round 1
// baseline (232.634 us; speedup 1.0000x reference)
//
#include <hip/hip_runtime.h>
#include <hip/hip_bf16.h>
#include <cfloat>
#include <math.h>

#define N_TOK   32768
#define S_CODES 1024
#define C_DIM   256

typedef __attribute__((ext_vector_type(8))) short short8v;
typedef __attribute__((ext_vector_type(4))) float float4v;

// ---- workspace byte offsets ----
#define WS_HIST 0                       // 1024 int
#define WS_LOSS 4096                    // 1 float
#define WS_W2   4608                    // 1024 float
#define WS_WPK  16384                   // w_packed [1024 codes][8 kc][hi 64B | lo 64B] = 1 MB
#define WS_NEED ((size_t)(WS_WPK + 1048576))

__device__ __forceinline__ unsigned short f2bf(float f) {
    __hip_bfloat16 h = __float2bfloat16(f);
    return __builtin_bit_cast(unsigned short, h);
}
__device__ __forceinline__ float bf2f(unsigned short u) {
    return __bfloat162float(__builtin_bit_cast(__hip_bfloat16, u));
}

// ---- split w into packed hi/lo rows + squared norms; also zero hist/loss ----
__global__ void split_w(const float* __restrict__ w, unsigned short* __restrict__ wpack,
                        float* __restrict__ w2, int* __restrict__ hist,
                        float* __restrict__ lossp) {
    int c = blockIdx.x, l = threadIdx.x;       // 1024 blocks x 64 threads
    float4 v = ((const float4*)(w + (size_t)c * C_DIM))[l];   // k = l*4 .. +3
    float s = v.x*v.x + v.y*v.y + v.z*v.z + v.w*v.w;
    float vv[4] = {v.x, v.y, v.z, v.w};
    ushort4 h4, l4;
    unsigned short* hp = (unsigned short*)&h4;
    unsigned short* lp = (unsigned short*)&l4;
#pragma unroll
    for (int q = 0; q < 4; ++q) {
        hp[q] = f2bf(vv[q]);
        lp[q] = f2bf(vv[q] - bf2f(hp[q]));
    }
    // kc = l>>3 (32-k chunk), offset within chunk = (l&7)*4 shorts
    size_t base = ((size_t)c * 8 + (l >> 3)) * 64;            // 64 shorts = 128 B per (c,kc)
    *(ushort4*)&wpack[base + (l & 7) * 4] = h4;               // hi half (bytes 0..63)
    *(ushort4*)&wpack[base + 32 + (l & 7) * 4] = l4;          // lo half (bytes 64..127)
#pragma unroll
    for (int off = 32; off > 0; off >>= 1) s += __shfl_down(s, off);
    if (l == 0) w2[c] = s;
    if (l == 32) hist[c] = 0;
    if (c == 0 && l == 33) *lossp = 0.f;
}

// ---- main: 128-token blocks, 8 waves (2 token-halves x 4 code-quarters).
//      x converted once to full-K LDS hi/lo (128 KB); W fragments loaded DIRECT
//      global->VGPR from L2-resident wpack (no W LDS staging, no main-loop barriers).
//      Wave tile 64 tok x 64 codes (i=4, j=4): per kc-step 8 ds_read + 8 global
//      b128 loads feed 48 MFMAs. grid 256 = 1 block/CU. ----
__global__ void __launch_bounds__(512, 2)
vq_fused2(const float* __restrict__ x, const float* __restrict__ emb,
          const unsigned short* __restrict__ wpack, const float* __restrict__ w2g,
          float* __restrict__ out, int* __restrict__ hist, float* __restrict__ lossp) {
    __shared__ __align__(16) char smem[147968];
    // layout: xh [128 tok][256 k] bf16 (64 KB) | xl (64 KB) | scratch 16.9 KB
    unsigned short* xh = (unsigned short*)smem;
    unsigned short* xl = (unsigned short*)(smem + 65536);
    char* scr = smem + 131072;

    const int tid = threadIdx.x;
    const int l = tid & 63, wv = tid >> 6;
    const int quad = l >> 4, lr = l & 15;
    const int th = wv >> 2, cq = wv & 3;       // token half / code quarter
    const int t0 = blockIdx.x * 128;
    const int b = t0 >> 10, hw0 = t0 & 1023;
    const size_t xbase = ((size_t)b << 18) + hw0;

    // ---- phase 1: stage + convert x (once) ----
    float x2tok = 0.f;                        // valid in tid<128 (token = tid)
    {
        float* xf32 = (float*)scr;            // [32 k][132] padded
        const int srow = tid >> 4, scol = (tid & 15) * 8;
        const int ct = tid & 127, kq = tid >> 7;
        float x2p = 0.f;
        for (int kc = 0; kc < 8; ++kc) {
            __syncthreads();                  // xf32 free
            const float* gp = x + xbase + (size_t)(kc * 32 + srow) * 1024 + scol;
            float4 a0 = *(const float4*)gp;
            float4 a1 = *(const float4*)(gp + 4);
            *(float4*)&xf32[srow * 132 + scol] = a0;
            *(float4*)&xf32[srow * 132 + scol + 4] = a1;
            __syncthreads();                  // xf32 ready
            short8v hv, lv;
#pragma unroll
            for (int j2 = 0; j2 < 8; ++j2) {
                float v = xf32[(kq * 8 + j2) * 132 + ct];
                unsigned short h = f2bf(v);
                float hf = bf2f(h);
                unsigned short lo = f2bf(v - hf);
                hv[j2] = (short)h; lv[j2] = (short)lo;
                x2p = fmaf(v, v, x2p);
            }
            int pos = (kc * 4 + kq) ^ (ct & 31);          // XOR swizzle, 16B chunks
            *(short8v*)&xh[ct * 256 + pos * 8] = hv;
            *(short8v*)&xl[ct * 256 + pos * 8] = lv;
        }
        __syncthreads();
        float* x2sh = (float*)scr;            // [4][128]
        x2sh[kq * 128 + ct] = x2p;
        __syncthreads();
        if (tid < 128)
            x2tok = x2sh[tid] + x2sh[128 + tid] + x2sh[256 + tid] + x2sh[384 + tid];
        __syncthreads();                      // xh/xl complete; scr free
    }

    // ---- precomputed A fragment offsets ----
    int aoffb[4], axor[4];
#pragma unroll
    for (int i = 0; i < 4; ++i) {
        int arow = th * 64 + i * 16 + lr;
        aoffb[i] = arow * 512;                // bytes (row = 256 shorts)
        axor[i] = arow & 31;
    }
    const char* wpc = (const char*)wpack;
    const int qb = quad * 16;                 // byte offset of this lane's k-chunk

    float bval[16]; int bidx[16];
#pragma unroll
    for (int s2 = 0; s2 < 16; ++s2) { bval[s2] = FLT_MAX; bidx[s2] = 0; }
    const float4v zacc = {0.f, 0.f, 0.f, 0.f};

    // ---- phase 2: 4 strips x 8 kc, barrier-free K-loop ----
    for (int s = 0; s < 4; ++s) {
        const int cbase = s * 256 + cq * 64;
        float4v acc[4][4];
#pragma unroll
        for (int i = 0; i < 4; ++i)
#pragma unroll
            for (int j = 0; j < 4; ++j) acc[i][j] = zacc;

#pragma unroll
        for (int kc = 0; kc < 8; ++kc) {
            // B fragments: direct global loads (L2-resident wpack), lane = (quad,lr)
            short8v bh[4], bl[4];
#pragma unroll
            for (int j = 0; j < 4; ++j) {
                size_t src = ((size_t)(cbase + j * 16 + lr) * 8 + kc) * 128 + qb;
                bh[j] = *(const short8v*)(wpc + src);
                bl[j] = *(const short8v*)(wpc + src + 64);
            }
            // A fragments from swizzled LDS
            short8v ah[4], al[4];
#pragma unroll
            for (int i = 0; i < 4; ++i) {
                int pos = ((kc * 4 + quad) ^ axor[i]) * 16;
                ah[i] = *(const short8v*)(smem + aoffb[i] + pos);
                al[i] = *(const short8v*)(smem + 65536 + aoffb[i] + pos);
            }
#pragma unroll
            for (int i = 0; i < 4; ++i)
#pragma unroll
                for (int j = 0; j < 4; ++j) {
                    acc[i][j] = __builtin_amdgcn_mfma_f32_16x16x32_bf16(ah[i], bh[j], acc[i][j], 0, 0, 0);
                    acc[i][j] = __builtin_amdgcn_mfma_f32_16x16x32_bf16(ah[i], bl[j], acc[i][j], 0, 0, 0);
                    acc[i][j] = __builtin_amdgcn_mfma_f32_16x16x32_bf16(al[i], bh[j], acc[i][j], 0, 0, 0);
                }
        }
        // fold strip into running per-token argmin
#pragma unroll
        for (int j = 0; j < 4; ++j) {
            int code = cbase + j * 16 + lr;
            float w2c = w2g[code];
#pragma unroll
            for (int i = 0; i < 4; ++i)
#pragma unroll
                for (int rr = 0; rr < 4; ++rr) {
                    float sv = fmaf(-2.f, acc[i][j][rr], w2c);
                    int slot = i * 4 + rr;
                    if (sv < bval[slot]) { bval[slot] = sv; bidx[slot] = code; }
                }
        }
    }

    // ---- phase 3: argmin reduce, histogram, loss, gather/write ----
    __syncthreads();
    float* bestv = (float*)scr;               // [8][64]
    int*   besti = (int*)(scr + 2048);        // [8][64]
    int*   idx_sh = (int*)(scr + 4096);       // [128]
#pragma unroll
    for (int slot = 0; slot < 16; ++slot) {
        float bv = bval[slot]; int bi = bidx[slot];
#pragma unroll
        for (int off = 1; off < 16; off <<= 1) {
            float ov = __shfl_xor(bv, off);
            int   oi = __shfl_xor(bi, off);
            if (ov < bv || (ov == bv && oi < bi)) { bv = ov; bi = oi; }
        }
        if (lr == 0) {
            int tloc = (slot >> 2) * 16 + quad * 4 + (slot & 3);   // 0..63 in half
            bestv[wv * 64 + tloc] = bv; besti[wv * 64 + tloc] = bi;
        }
    }
    __syncthreads();
    if (tid < 128) {
        int th2 = tid >> 6, tl = tid & 63;
        float bv = bestv[(th2 * 4) * 64 + tl]; int bi = besti[(th2 * 4) * 64 + tl];
#pragma unroll
        for (int w = 1; w < 4; ++w) {
            float ov = bestv[(th2 * 4 + w) * 64 + tl];
            int   oi = besti[(th2 * 4 + w) * 64 + tl];
            if (ov < bv || (ov == bv && oi < bi)) { bv = ov; bi = oi; }
        }
        idx_sh[tid] = bi;
        atomicAdd(&hist[bi], 1);
        float lsum = bv + x2tok;              // |q-x|^2 = (w2 - 2 q.x) + x^2
#pragma unroll
        for (int off = 32; off > 0; off >>= 1) lsum += __shfl_down(lsum, off);
        if ((tid & 63) == 0) atomicAdd(lossp, lsum);
    }
    __syncthreads();
    {
        int t = tid & 127, cg = tid >> 7;
        int id = idx_sh[t];
        const float* erow = emb + (size_t)id * C_DIM;
        float* ob = out + xbase + t;
#pragma unroll
        for (int cb = 0; cb < 16; ++cb) {
            int c4 = cb * 16 + cg * 4;
            float4 q4 = *(const float4*)&erow[c4];
            ob[(size_t)(c4 + 0) * 1024] = q4.x;
            ob[(size_t)(c4 + 1) * 1024] = q4.y;
            ob[(size_t)(c4 + 2) * 1024] = q4.z;
            ob[(size_t)(c4 + 3) * 1024] = q4.w;
        }
    }
}

__global__ void finalize_kernel(const int* __restrict__ hist, const float* __restrict__ lossp,
                                float* __restrict__ out) {
    __shared__ float red[16];
    int tid = threadIdx.x;                  // 1024 threads
    float p = (float)hist[tid] * (1.f / 32768.f);
    float term = p * logf(p + 1e-6f);
#pragma unroll
    for (int off = 32; off > 0; off >>= 1) term += __shfl_down(term, off);
    if ((tid & 63) == 0) red[tid >> 6] = term;
    __syncthreads();
    if (tid == 0) {
        float s = 0.f;
#pragma unroll
        for (int i = 0; i < 16; ++i) s += red[i];
        out[8388608] = 0.25f * lossp[0] * (1.f / 8388608.f);   // quant_loss
        out[8388609] = expf(-s);                               // perplexity
    }
}

// ---- fallback path (round-1 kernel, known-correct) used only if ws too small ----
__global__ void w2_kernel(const float* __restrict__ w, float* __restrict__ w2) {
    int code = blockIdx.x * blockDim.x + threadIdx.x;
    const float4* r = (const float4*)(w + (size_t)code * C_DIM);
    float s = 0.f;
#pragma unroll 8
    for (int i = 0; i < C_DIM / 4; ++i) {
        float4 v = r[i];
        s += v.x * v.x + v.y * v.y + v.z * v.z + v.w * v.w;
    }
    w2[code] = s;
}

__launch_bounds__(256, 2)
__global__ void vq_main(const float* __restrict__ x, const float* __restrict__ emb,
                        float* __restrict__ out, int* __restrict__ hist,
                        float* __restrict__ lossp, const float* __restrict__ w2) {
    __shared__ float w_lds[8 * S_CODES];
    __shared__ float x_lds[C_DIM * 32];
    const int tid = threadIdx.x;
    const int l = tid & 63, wv = tid >> 6;
    const int t0 = blockIdx.x * 32;
    const int b = t0 >> 10, hw0 = t0 & 1023;
    const float* xbase = x + ((size_t)b * C_DIM << 10) + hw0;
    {
        int rl = tid & 7, r0 = tid >> 3;
        for (int rep = 0; rep < 8; ++rep) {
            int c = rep * 32 + r0;
            float4 v = *(const float4*)(xbase + ((size_t)c << 10) + rl * 4);
            *(float4*)&x_lds[c * 32 + rl * 4] = v;
        }
    }
    float4 pre[8];
#pragma unroll
    for (int m = 0; m < 8; ++m) {
        int fid = m * 256 + tid;
        int code = fid >> 1, kq = fid & 1;
        pre[m] = *(const float4*)(emb + (size_t)code * C_DIM + kq * 4);
    }
    float acc[8][16];
#pragma unroll
    for (int t = 0; t < 8; ++t)
#pragma unroll
        for (int j = 0; j < 16; ++j) acc[t][j] = 0.f;
    __syncthreads();
    for (int chunk = 0; chunk < 32; ++chunk) {
#pragma unroll
        for (int m = 0; m < 8; ++m) {
            int fid = m * 256 + tid;
            int code = fid >> 1, kq = fid & 1;
            float4 v = pre[m];
            w_lds[(kq * 4 + 0) * S_CODES + code] = v.x;
            w_lds[(kq * 4 + 1) * S_CODES + code] = v.y;
            w_lds[(kq * 4 + 2) * S_CODES + code] = v.z;
            w_lds[(kq * 4 + 3) * S_CODES + code] = v.w;
        }
        if (chunk + 1 < 32) {
            int k0n = (chunk + 1) * 8;
#pragma unroll
            for (int m = 0; m < 8; ++m) {
                int fid = m * 256 + tid;
                int code = fid >> 1, kq = fid & 1;
                pre[m] = *(const float4*)(emb + (size_t)code * C_DIM + k0n + kq * 4);
            }
        }
        __syncthreads();
        int k0 = chunk * 8;
#pragma unroll
        for (int kk = 0; kk < 8; ++kk) {
            int k = k0 + kk;
            float4 wq0 = *(const float4*)&w_lds[kk * S_CODES +   0 + l * 4];
            float4 wq1 = *(const float4*)&w_lds[kk * S_CODES + 256 + l * 4];
            float4 wq2 = *(const float4*)&w_lds[kk * S_CODES + 512 + l * 4];
            float4 wq3 = *(const float4*)&w_lds[kk * S_CODES + 768 + l * 4];
            float4 xa = *(const float4*)&x_lds[k * 32 + wv * 8];
            float4 xb = *(const float4*)&x_lds[k * 32 + wv * 8 + 4];
            float xs[8] = {xa.x, xa.y, xa.z, xa.w, xb.x, xb.y, xb.z, xb.w};
            float wvv[16] = {wq0.x, wq0.y, wq0.z, wq0.w, wq1.x, wq1.y, wq1.z, wq1.w,
                             wq2.x, wq2.y, wq2.z, wq2.w, wq3.x, wq3.y, wq3.z, wq3.w};
#pragma unroll
            for (int t = 0; t < 8; ++t) {
                float xv = xs[t];
#pragma unroll
                for (int j = 0; j < 16; ++j) acc[t][j] = fmaf(xv, wvv[j], acc[t][j]);
            }
        }
        __syncthreads();
    }
    float w2v[16];
#pragma unroll
    for (int m = 0; m < 4; ++m) {
        float4 v = *(const float4*)&w2[m * 256 + l * 4];
        w2v[m*4+0] = v.x; w2v[m*4+1] = v.y; w2v[m*4+2] = v.z; w2v[m*4+3] = v.w;
    }
    int* idx_sh = (int*)w_lds;
    float* red = (float*)(w_lds + 64);
#pragma unroll
    for (int t = 0; t < 8; ++t) {
        float bv = FLT_MAX; int bi = 0;
#pragma unroll
        for (int m = 0; m < 4; ++m)
#pragma unroll
            for (int j = 0; j < 4; ++j) {
                float s = w2v[m*4+j] - 2.f * acc[t][m*4+j];
                int c = m * 256 + l * 4 + j;
                if (s < bv) { bv = s; bi = c; }
            }
#pragma unroll
        for (int off = 32; off > 0; off >>= 1) {
            float ov = __shfl_xor(bv, off);
            int oi = __shfl_xor(bi, off);
            if (ov < bv || (ov == bv && oi < bi)) { bv = ov; bi = oi; }
        }
        if (l == 0) idx_sh[wv * 8 + t] = bi;
    }
    __syncthreads();
    if (tid < 32) atomicAdd(&hist[idx_sh[tid]], 1);
    float lsum = 0.f;
    for (int e = tid; e < C_DIM * 32; e += 256) {
        int t = e & 31, c = e >> 5;
        int id = idx_sh[t];
        float q = emb[(size_t)id * C_DIM + c];
        float xv = x_lds[c * 32 + t];
        float d = q - xv;
        lsum += d * d;
        out[((size_t)(b * C_DIM + c) << 10) + hw0 + t] = q;
    }
#pragma unroll
    for (int off = 32; off > 0; off >>= 1) lsum += __shfl_down(lsum, off);
    if (l == 0) red[wv] = lsum;
    __syncthreads();
    if (tid == 0) atomicAdd(lossp, red[0] + red[1] + red[2] + red[3]);
}

extern "C" void kernel_launch(void* const* d_in, const int* in_sizes, int n_in,
                              void* d_out, int out_size, void* d_ws, size_t ws_size,
                              hipStream_t stream) {
    const float* x   = (const float*)d_in[0];
    const float* emb = (const float*)d_in[1];
    float* out = (float*)d_out;
    char* ws = (char*)d_ws;
    int*   hist  = (int*)(ws + WS_HIST);
    float* lossp = (float*)(ws + WS_LOSS);
    float* w2    = (float*)(ws + WS_W2);

    if (ws_size >= WS_NEED) {
        unsigned short* wpack = (unsigned short*)(ws + WS_WPK);
        split_w<<<1024, 64, 0, stream>>>(emb, wpack, w2, hist, lossp);
        vq_fused2<<<256, 512, 0, stream>>>(x, emb, wpack, w2, out, hist, lossp);
    } else {
        hipMemsetAsync(d_ws, 0, 4608, stream);
        w2_kernel<<<4, 256, 0, stream>>>(emb, w2);
        vq_main<<<1024, 256, 0, stream>>>(x, emb, out, hist, lossp, w2);
    }
    finalize_kernel<<<1, 1024, 0, stream>>>(hist, lossp, out);
}

// Round 2
// 186.076 us; speedup vs baseline: 1.2502x; 1.2502x over previous
//
#include <hip/hip_runtime.h>
#include <hip/hip_bf16.h>
#include <cfloat>
#include <math.h>

#define N_TOK   32768
#define S_CODES 1024
#define C_DIM   256

typedef __attribute__((ext_vector_type(8))) short short8v;
typedef __attribute__((ext_vector_type(4))) float float4v;

// ---- workspace byte offsets ----
#define WS_HIST 0                       // 1024 int
#define WS_LOSS 4096                    // 1 float
#define WS_W2   4608                    // 1024 float
#define WS_WPK  16384                   // w_packed [1024 codes][8 kc][hi 64B | lo 64B] = 1 MB
#define WS_NEED ((size_t)(WS_WPK + 1048576))

__device__ __forceinline__ unsigned short f2bf(float f) {
    __hip_bfloat16 h = __float2bfloat16(f);
    return __builtin_bit_cast(unsigned short, h);
}
__device__ __forceinline__ float bf2f(unsigned short u) {
    return __bfloat162float(__builtin_bit_cast(__hip_bfloat16, u));
}
__device__ __forceinline__ void gload16(const void* g, void* l) {
    __builtin_amdgcn_global_load_lds((const __attribute__((address_space(1))) void*)g,
                                     (__attribute__((address_space(3))) void*)l, 16, 0, 0);
}

// ---- split w into packed hi/lo rows + squared norms; also zero hist/loss ----
__global__ void split_w(const float* __restrict__ w, unsigned short* __restrict__ wpack,
                        float* __restrict__ w2, int* __restrict__ hist,
                        float* __restrict__ lossp) {
    int c = blockIdx.x, l = threadIdx.x;       // 1024 blocks x 64 threads
    float4 v = ((const float4*)(w + (size_t)c * C_DIM))[l];   // k = l*4 .. +3
    float s = v.x*v.x + v.y*v.y + v.z*v.z + v.w*v.w;
    float vv[4] = {v.x, v.y, v.z, v.w};
    ushort4 h4, l4;
    unsigned short* hp = (unsigned short*)&h4;
    unsigned short* lp = (unsigned short*)&l4;
#pragma unroll
    for (int q = 0; q < 4; ++q) {
        hp[q] = f2bf(vv[q]);
        lp[q] = f2bf(vv[q] - bf2f(hp[q]));
    }
    size_t base = ((size_t)c * 8 + (l >> 3)) * 64;            // 64 shorts = 128 B per (c,kc)
    *(ushort4*)&wpack[base + (l & 7) * 4] = h4;               // hi half (bytes 0..63)
    *(ushort4*)&wpack[base + 32 + (l & 7) * 4] = l4;          // lo half (bytes 64..127)
#pragma unroll
    for (int off = 32; off > 0; off >>= 1) s += __shfl_down(s, off);
    if (l == 0) w2[c] = s;
    if (l == 32) hist[c] = 0;
    if (c == 0 && l == 33) *lossp = 0.f;
}

// ---- main: 128-token blocks, 8 waves (th = wv&1 token-half, cq = wv>>1 code-quarter).
//      x converted once to full-K LDS hi/lo (128 KB). W staged via global_load_lds in
//      8 KB quarter-tiles (64 codes x one kc), double-buffered, counted vmcnt(1) +
//      raw barriers so the DMA overlaps compute. Wave tile 64 tok x 64 codes.
//      grid 256 = 1 block/CU, LDS 147968 -> 8 waves (2/SIMD). ----
__global__ void __launch_bounds__(512, 2)
vq_fused3(const float* __restrict__ x, const float* __restrict__ emb,
          const unsigned short* __restrict__ wpack, const float* __restrict__ w2g,
          float* __restrict__ out, int* __restrict__ hist, float* __restrict__ lossp) {
    __shared__ __align__(16) char smem[147968];
    // layout: xh [128 tok][256 k] bf16 (64 KB) | xl (64 KB) | W dbuf 2x8KB / scratch 16.9KB
    unsigned short* xh = (unsigned short*)smem;
    unsigned short* xl = (unsigned short*)(smem + 65536);
    char* wbuf = smem + 131072;               // two 8 KB quarter-tile buffers
    char* scr  = smem + 131072;               // phase-1/3 scratch overlay (16.9 KB)

    const int tid = threadIdx.x;
    const int l = tid & 63, wv = tid >> 6;
    const int quad = l >> 4, lr = l & 15;
    const int th = wv & 1, cq = wv >> 1;      // SIMD (wv&3) hosts cq and cq+2 -> alternating MFMA
    const int t0 = blockIdx.x * 128;
    const int b = t0 >> 10, hw0 = t0 & 1023;
    const size_t xbase = ((size_t)b << 18) + hw0;

    // ---- phase 1: stage + convert x (once) ----
    float x2tok = 0.f;                        // valid in tid<128 (token = tid)
    {
        float* xf32 = (float*)scr;            // [32 k][132] padded
        const int srow = tid >> 4, scol = (tid & 15) * 8;
        const int ct = tid & 127, kq = tid >> 7;
        float x2p = 0.f;
        for (int kc = 0; kc < 8; ++kc) {
            __syncthreads();                  // xf32 free
            const float* gp = x + xbase + (size_t)(kc * 32 + srow) * 1024 + scol;
            float4 a0 = *(const float4*)gp;
            float4 a1 = *(const float4*)(gp + 4);
            *(float4*)&xf32[srow * 132 + scol] = a0;
            *(float4*)&xf32[srow * 132 + scol + 4] = a1;
            __syncthreads();                  // xf32 ready
            short8v hv, lv;
#pragma unroll
            for (int j2 = 0; j2 < 8; ++j2) {
                float v = xf32[(kq * 8 + j2) * 132 + ct];
                unsigned short h = f2bf(v);
                float hf = bf2f(h);
                unsigned short lo = f2bf(v - hf);
                hv[j2] = (short)h; lv[j2] = (short)lo;
                x2p = fmaf(v, v, x2p);
            }
            int pos = (kc * 4 + kq) ^ (ct & 31);          // XOR swizzle, 16B chunks
            *(short8v*)&xh[ct * 256 + pos * 8] = hv;
            *(short8v*)&xl[ct * 256 + pos * 8] = lv;
        }
        __syncthreads();
        float* x2sh = (float*)scr;            // [4][128]
        x2sh[kq * 128 + ct] = x2p;
        __syncthreads();
        if (tid < 128)
            x2tok = x2sh[tid] + x2sh[128 + tid] + x2sh[256 + tid] + x2sh[384 + tid];
        __syncthreads();                      // xh/xl complete; scr free
    }

    // ---- precomputed fragment offsets ----
    int aoffb[4], axor[4];
#pragma unroll
    for (int i = 0; i < 4; ++i) {
        int arow = th * 64 + i * 16 + lr;     // token row
        aoffb[i] = arow * 512;                // bytes (row = 256 shorts)
        axor[i] = arow & 31;
    }
    int boff_h[4], boff_l[4];
#pragma unroll
    for (int j = 0; j < 4; ++j) {
        int brow = j * 16 + lr;               // row within 64-code quarter-tile, 128 B rows
        boff_h[j] = brow * 128 + ((quad ^ (brow & 7)) * 16);
        boff_l[j] = brow * 128 + (((4 + quad) ^ (brow & 7)) * 16);
    }
    const int drq = l >> 3;                   // DMA: row within 8-row group
    const int dch = (l & 7) ^ (drq & 7);      // source chunk (un-swizzle)
    const char* wpc = (const char*)wpack;
    const char* bufp = wbuf + (cq & 1) * 8192;   // this wave always reads buf[cq&1]

    float bval[16]; int bidx[16];
#pragma unroll
    for (int s2 = 0; s2 < 16; ++s2) { bval[s2] = FLT_MAX; bidx[s2] = 0; }
    const float4v zacc = {0.f, 0.f, 0.f, 0.f};

    // stage quarter-tile for global step gs into wbuf[gs&1]; 8 waves x 1 KB
    auto STAGE = [&](int gs) {
        int sp = gs >> 5, kcp = (gs >> 2) & 7, qp = gs & 3;
        int lrow = wv * 8;
        int code = sp * 256 + qp * 64 + lrow + drq;
        size_t src = ((size_t)code * 8 + kcp) * 128 + (size_t)dch * 16;
        gload16(wpc + src, wbuf + (gs & 1) * 8192 + lrow * 128);
    };

    // ---- phase 2: 128 pipelined steps (4 strips x 8 kc x 4 quarters) ----
    STAGE(0);
#pragma unroll 1
    for (int s = 0; s < 4; ++s) {
        float4v acc[4][4];
#pragma unroll
        for (int i = 0; i < 4; ++i)
#pragma unroll
            for (int j = 0; j < 4; ++j) acc[i][j] = zacc;

#pragma unroll 1
        for (int kc = 0; kc < 8; ++kc) {
#pragma unroll 1
            for (int q = 0; q < 4; ++q) {
                int g = s * 32 + kc * 4 + q;
                if (g < 127) {
                    STAGE(g + 1);
                    asm volatile("s_waitcnt vmcnt(1)" ::: "memory");  // step-g DMA done
                } else {
                    asm volatile("s_waitcnt vmcnt(0)" ::: "memory");
                }
                __builtin_amdgcn_s_barrier();             // all waves' g-parts visible
                if (q == cq) {
                    short8v ah[4], al[4], bh[4], bl[4];
#pragma unroll
                    for (int i = 0; i < 4; ++i) {
                        int pos = ((kc * 4 + quad) ^ axor[i]) * 16;
                        ah[i] = *(const short8v*)(smem + aoffb[i] + pos);
                        al[i] = *(const short8v*)(smem + 65536 + aoffb[i] + pos);
                    }
#pragma unroll
                    for (int j = 0; j < 4; ++j) {
                        bh[j] = *(const short8v*)(bufp + boff_h[j]);
                        bl[j] = *(const short8v*)(bufp + boff_l[j]);
                    }
                    __builtin_amdgcn_s_setprio(1);
#pragma unroll
                    for (int i = 0; i < 4; ++i)
#pragma unroll
                        for (int j = 0; j < 4; ++j) {
                            acc[i][j] = __builtin_amdgcn_mfma_f32_16x16x32_bf16(ah[i], bh[j], acc[i][j], 0, 0, 0);
                            acc[i][j] = __builtin_amdgcn_mfma_f32_16x16x32_bf16(ah[i], bl[j], acc[i][j], 0, 0, 0);
                            acc[i][j] = __builtin_amdgcn_mfma_f32_16x16x32_bf16(al[i], bh[j], acc[i][j], 0, 0, 0);
                        }
                    __builtin_amdgcn_s_setprio(0);
                }
                __builtin_amdgcn_s_barrier();             // reads done before buf reuse
            }
        }
        // fold strip into running per-token argmin
#pragma unroll
        for (int j = 0; j < 4; ++j) {
            int code = s * 256 + cq * 64 + j * 16 + lr;
            float w2c = w2g[code];
#pragma unroll
            for (int i = 0; i < 4; ++i)
#pragma unroll
                for (int rr = 0; rr < 4; ++rr) {
                    float sv = fmaf(-2.f, acc[i][j][rr], w2c);
                    int slot = i * 4 + rr;
                    if (sv < bval[slot]) { bval[slot] = sv; bidx[slot] = code; }
                }
        }
    }

    // ---- phase 3: argmin reduce, histogram, loss, gather/write ----
    __syncthreads();                          // scr free (wbuf reads done)
    float* bestv = (float*)scr;               // [8][64]
    int*   besti = (int*)(scr + 2048);        // [8][64]
    int*   idx_sh = (int*)(scr + 4096);       // [128]
#pragma unroll
    for (int slot = 0; slot < 16; ++slot) {
        float bv = bval[slot]; int bi = bidx[slot];
#pragma unroll
        for (int off = 1; off < 16; off <<= 1) {
            float ov = __shfl_xor(bv, off);
            int   oi = __shfl_xor(bi, off);
            if (ov < bv || (ov == bv && oi < bi)) { bv = ov; bi = oi; }
        }
        if (lr == 0) {
            int tloc = (slot >> 2) * 16 + quad * 4 + (slot & 3);   // 0..63 within half
            bestv[wv * 64 + tloc] = bv; besti[wv * 64 + tloc] = bi;
        }
    }
    __syncthreads();
    if (tid < 128) {
        int th2 = tid >> 6, tl = tid & 63;    // waves with th==th2: {th2, th2+2, th2+4, th2+6}
        float bv = bestv[th2 * 64 + tl]; int bi = besti[th2 * 64 + tl];
#pragma unroll
        for (int w = 1; w < 4; ++w) {
            float ov = bestv[(w * 2 + th2) * 64 + tl];
            int   oi = besti[(w * 2 + th2) * 64 + tl];
            if (ov < bv || (ov == bv && oi < bi)) { bv = ov; bi = oi; }
        }
        idx_sh[tid] = bi;
        atomicAdd(&hist[bi], 1);
        float lsum = bv + x2tok;              // |q-x|^2 = (w2 - 2 q.x) + x^2
#pragma unroll
        for (int off = 32; off > 0; off >>= 1) lsum += __shfl_down(lsum, off);
        if ((tid & 63) == 0) atomicAdd(lossp, lsum);
    }
    __syncthreads();
    {
        int t = tid & 127, cg = tid >> 7;
        int id = idx_sh[t];
        const float* erow = emb + (size_t)id * C_DIM;
        float* ob = out + xbase + t;
#pragma unroll
        for (int cb = 0; cb < 16; ++cb) {
            int c4 = cb * 16 + cg * 4;
            float4 q4 = *(const float4*)&erow[c4];
            ob[(size_t)(c4 + 0) * 1024] = q4.x;
            ob[(size_t)(c4 + 1) * 1024] = q4.y;
            ob[(size_t)(c4 + 2) * 1024] = q4.z;
            ob[(size_t)(c4 + 3) * 1024] = q4.w;
        }
    }
}

__global__ void finalize_kernel(const int* __restrict__ hist, const float* __restrict__ lossp,
                                float* __restrict__ out) {
    __shared__ float red[16];
    int tid = threadIdx.x;                  // 1024 threads
    float p = (float)hist[tid] * (1.f / 32768.f);
    float term = p * logf(p + 1e-6f);
#pragma unroll
    for (int off = 32; off > 0; off >>= 1) term += __shfl_down(term, off);
    if ((tid & 63) == 0) red[tid >> 6] = term;
    __syncthreads();
    if (tid == 0) {
        float s = 0.f;
#pragma unroll
        for (int i = 0; i < 16; ++i) s += red[i];
        out[8388608] = 0.25f * lossp[0] * (1.f / 8388608.f);   // quant_loss
        out[8388609] = expf(-s);                               // perplexity
    }
}

// ---- fallback path (round-1 kernel, known-correct) used only if ws too small ----
__global__ void w2_kernel(const float* __restrict__ w, float* __restrict__ w2) {
    int code = blockIdx.x * blockDim.x + threadIdx.x;
    const float4* r = (const float4*)(w + (size_t)code * C_DIM);
    float s = 0.f;
#pragma unroll 8
    for (int i = 0; i < C_DIM / 4; ++i) {
        float4 v = r[i];
        s += v.x * v.x + v.y * v.y + v.z * v.z + v.w * v.w;
    }
    w2[code] = s;
}

__launch_bounds__(256, 2)
__global__ void vq_main(const float* __restrict__ x, const float* __restrict__ emb,
                        float* __restrict__ out, int* __restrict__ hist,
                        float* __restrict__ lossp, const float* __restrict__ w2) {
    __shared__ float w_lds[8 * S_CODES];
    __shared__ float x_lds[C_DIM * 32];
    const int tid = threadIdx.x;
    const int l = tid & 63, wv = tid >> 6;
    const int t0 = blockIdx.x * 32;
    const int b = t0 >> 10, hw0 = t0 & 1023;
    const float* xbase = x + ((size_t)b * C_DIM << 10) + hw0;
    {
        int rl = tid & 7, r0 = tid >> 3;
        for (int rep = 0; rep < 8; ++rep) {
            int c = rep * 32 + r0;
            float4 v = *(const float4*)(xbase + ((size_t)c << 10) + rl * 4);
            *(float4*)&x_lds[c * 32 + rl * 4] = v;
        }
    }
    float4 pre[8];
#pragma unroll
    for (int m = 0; m < 8; ++m) {
        int fid = m * 256 + tid;
        int code = fid >> 1, kq = fid & 1;
        pre[m] = *(const float4*)(emb + (size_t)code * C_DIM + kq * 4);
    }
    float acc[8][16];
#pragma unroll
    for (int t = 0; t < 8; ++t)
#pragma unroll
        for (int j = 0; j < 16; ++j) acc[t][j] = 0.f;
    __syncthreads();
    for (int chunk = 0; chunk < 32; ++chunk) {
#pragma unroll
        for (int m = 0; m < 8; ++m) {
            int fid = m * 256 + tid;
            int code = fid >> 1, kq = fid & 1;
            float4 v = pre[m];
            w_lds[(kq * 4 + 0) * S_CODES + code] = v.x;
            w_lds[(kq * 4 + 1) * S_CODES + code] = v.y;
            w_lds[(kq * 4 + 2) * S_CODES + code] = v.z;
            w_lds[(kq * 4 + 3) * S_CODES + code] = v.w;
        }
        if (chunk + 1 < 32) {
            int k0n = (chunk + 1) * 8;
#pragma unroll
            for (int m = 0; m < 8; ++m) {
                int fid = m * 256 + tid;
                int code = fid >> 1, kq = fid & 1;
                pre[m] = *(const float4*)(emb + (size_t)code * C_DIM + k0n + kq * 4);
            }
        }
        __syncthreads();
        int k0 = chunk * 8;
#pragma unroll
        for (int kk = 0; kk < 8; ++kk) {
            int k = k0 + kk;
            float4 wq0 = *(const float4*)&w_lds[kk * S_CODES +   0 + l * 4];
            float4 wq1 = *(const float4*)&w_lds[kk * S_CODES + 256 + l * 4];
            float4 wq2 = *(const float4*)&w_lds[kk * S_CODES + 512 + l * 4];
            float4 wq3 = *(const float4*)&w_lds[kk * S_CODES + 768 + l * 4];
            float4 xa = *(const float4*)&x_lds[k * 32 + wv * 8];
            float4 xb = *(const float4*)&x_lds[k * 32 + wv * 8 + 4];
            float xs[8] = {xa.x, xa.y, xa.z, xa.w, xb.x, xb.y, xb.z, xb.w};
            float wvv[16] = {wq0.x, wq0.y, wq0.z, wq0.w, wq1.x, wq1.y, wq1.z, wq1.w,
                             wq2.x, wq2.y, wq2.z, wq2.w, wq3.x, wq3.y, wq3.z, wq3.w};
#pragma unroll
            for (int t = 0; t < 8; ++t) {
                float xv = xs[t];
#pragma unroll
                for (int j = 0; j < 16; ++j) acc[t][j] = fmaf(xv, wvv[j], acc[t][j]);
            }
        }
        __syncthreads();
    }
    float w2v[16];
#pragma unroll
    for (int m = 0; m < 4; ++m) {
        float4 v = *(const float4*)&w2[m * 256 + l * 4];
        w2v[m*4+0] = v.x; w2v[m*4+1] = v.y; w2v[m*4+2] = v.z; w2v[m*4+3] = v.w;
    }
    int* idx_sh = (int*)w_lds;
    float* red = (float*)(w_lds + 64);
#pragma unroll
    for (int t = 0; t < 8; ++t) {
        float bv = FLT_MAX; int bi = 0;
#pragma unroll
        for (int m = 0; m < 4; ++m)
#pragma unroll
            for (int j = 0; j < 4; ++j) {
                float s = w2v[m*4+j] - 2.f * acc[t][m*4+j];
                int c = m * 256 + l * 4 + j;
                if (s < bv) { bv = s; bi = c; }
            }
#pragma unroll
        for (int off = 32; off > 0; off >>= 1) {
            float ov = __shfl_xor(bv, off);
            int oi = __shfl_xor(bi, off);
            if (ov < bv || (ov == bv && oi < bi)) { bv = ov; bi = oi; }
        }
        if (l == 0) idx_sh[wv * 8 + t] = bi;
    }
    __syncthreads();
    if (tid < 32) atomicAdd(&hist[idx_sh[tid]], 1);
    float lsum = 0.f;
    for (int e = tid; e < C_DIM * 32; e += 256) {
        int t = e & 31, c = e >> 5;
        int id = idx_sh[t];
        float q = emb[(size_t)id * C_DIM + c];
        float xv = x_lds[c * 32 + t];
        float d = q - xv;
        lsum += d * d;
        out[((size_t)(b * C_DIM + c) << 10) + hw0 + t] = q;
    }
#pragma unroll
    for (int off = 32; off > 0; off >>= 1) lsum += __shfl_down(lsum, off);
    if (l == 0) red[wv] = lsum;
    __syncthreads();
    if (tid == 0) atomicAdd(lossp, red[0] + red[1] + red[2] + red[3]);
}

extern "C" void kernel_launch(void* const* d_in, const int* in_sizes, int n_in,
                              void* d_out, int out_size, void* d_ws, size_t ws_size,
                              hipStream_t stream) {
    const float* x   = (const float*)d_in[0];
    const float* emb = (const float*)d_in[1];
    float* out = (float*)d_out;
    char* ws = (char*)d_ws;
    int*   hist  = (int*)(ws + WS_HIST);
    float* lossp = (float*)(ws + WS_LOSS);
    float* w2    = (float*)(ws + WS_W2);

    if (ws_size >= WS_NEED) {
        unsigned short* wpack = (unsigned short*)(ws + WS_WPK);
        split_w<<<1024, 64, 0, stream>>>(emb, wpack, w2, hist, lossp);
        vq_fused3<<<256, 512, 0, stream>>>(x, emb, wpack, w2, out, hist, lossp);
    } else {
        hipMemsetAsync(d_ws, 0, 4608, stream);
        w2_kernel<<<4, 256, 0, stream>>>(emb, w2);
        vq_main<<<1024, 256, 0, stream>>>(x, emb, out, hist, lossp, w2);
    }
    finalize_kernel<<<1, 1024, 0, stream>>>(hist, lossp, out);
}

// Round 3
// 158.626 us; speedup vs baseline: 1.4666x; 1.1730x over previous
//
#include <hip/hip_runtime.h>
#include <hip/hip_bf16.h>
#include <cfloat>
#include <math.h>

#define N_TOK   32768
#define S_CODES 1024
#define C_DIM   256

typedef __attribute__((ext_vector_type(8))) short short8v;
typedef __attribute__((ext_vector_type(4))) float float4v;

// ---- workspace byte offsets ----
#define WS_HIST 0                       // 1024 int
#define WS_LOSS 4096                    // 1 float
#define WS_W2   4608                    // 1024 float
#define WS_WPK  16384                   // w_packed [1024 codes][8 kc][hi 64B | lo 64B] = 1 MB
#define WS_NEED ((size_t)(WS_WPK + 1048576))

__device__ __forceinline__ unsigned short f2bf(float f) {
    __hip_bfloat16 h = __float2bfloat16(f);
    return __builtin_bit_cast(unsigned short, h);
}
__device__ __forceinline__ float bf2f(unsigned short u) {
    return __bfloat162float(__builtin_bit_cast(__hip_bfloat16, u));
}
__device__ __forceinline__ void gload16(const void* g, void* l) {
    __builtin_amdgcn_global_load_lds((const __attribute__((address_space(1))) void*)g,
                                     (__attribute__((address_space(3))) void*)l, 16, 0, 0);
}

// ---- split w into packed hi/lo rows + squared norms; also zero hist/loss ----
__global__ void split_w(const float* __restrict__ w, unsigned short* __restrict__ wpack,
                        float* __restrict__ w2, int* __restrict__ hist,
                        float* __restrict__ lossp) {
    int c = blockIdx.x, l = threadIdx.x;       // 1024 blocks x 64 threads
    float4 v = ((const float4*)(w + (size_t)c * C_DIM))[l];   // k = l*4 .. +3
    float s = v.x*v.x + v.y*v.y + v.z*v.z + v.w*v.w;
    float vv[4] = {v.x, v.y, v.z, v.w};
    ushort4 h4, l4;
    unsigned short* hp = (unsigned short*)&h4;
    unsigned short* lp = (unsigned short*)&l4;
#pragma unroll
    for (int q = 0; q < 4; ++q) {
        hp[q] = f2bf(vv[q]);
        lp[q] = f2bf(vv[q] - bf2f(hp[q]));
    }
    size_t base = ((size_t)c * 8 + (l >> 3)) * 64;            // 64 shorts = 128 B per (c,kc)
    *(ushort4*)&wpack[base + (l & 7) * 4] = h4;               // hi half (bytes 0..63)
    *(ushort4*)&wpack[base + 32 + (l & 7) * 4] = l4;          // lo half (bytes 64..127)
#pragma unroll
    for (int off = 32; off > 0; off >>= 1) s += __shfl_down(s, off);
    if (l == 0) w2[c] = s;
    if (l == 32) hist[c] = 0;
    if (c == 0 && l == 33) *lossp = 0.f;
}

// ---- main: 128-token blocks, 8 waves (th = wv&1 token-half, cq = wv>>1 code-quarter).
//      x converted once to full-K LDS hi/lo (128 KB). W staged via global_load_lds in
//      16 KB tiles (128 codes x one 32-k chunk), DOUBLE-BUFFERED with counted
//      vmcnt(2) so tile g+1's DMA overlaps tile g's compute. ALL 8 waves compute
//      every step: wave tile 64 tok x 32 codes (r0's proven per-wave geometry).
//      LDS 163840 B (full 160 KiB): 1 block/CU, 8 waves = 2/SIMD. ----
__global__ void __launch_bounds__(512, 2)
vq_fused4(const float* __restrict__ x, const float* __restrict__ emb,
          const unsigned short* __restrict__ wpack, const float* __restrict__ w2g,
          float* __restrict__ out, int* __restrict__ hist, float* __restrict__ lossp) {
    __shared__ __align__(16) char smem[163840];
    // layout: xh [128 tok][256 k] bf16 (64 KB) | xl (64 KB) | W dbuf 2x16 KB
    unsigned short* xh = (unsigned short*)smem;
    unsigned short* xl = (unsigned short*)(smem + 65536);
    char* wbuf = smem + 131072;               // two 16 KB tile buffers
    char* scr  = smem + 131072;               // phase-1/3 scratch overlay (32 KB)

    const int tid = threadIdx.x;
    const int l = tid & 63, wv = tid >> 6;
    const int quad = l >> 4, lr = l & 15;
    const int th = wv & 1, cq = wv >> 1;      // token half / code quarter
    const int t0 = blockIdx.x * 128;
    const int b = t0 >> 10, hw0 = t0 & 1023;
    const size_t xbase = ((size_t)b << 18) + hw0;

    // ---- phase 1: stage + convert x (once) ----
    float x2tok = 0.f;                        // valid in tid<128 (token = tid)
    {
        float* xf32 = (float*)scr;            // [32 k][132] padded (16.9 KB < 32 KB)
        const int srow = tid >> 4, scol = (tid & 15) * 8;
        const int ct = tid & 127, kq = tid >> 7;
        float x2p = 0.f;
        for (int kc = 0; kc < 8; ++kc) {
            __syncthreads();                  // xf32 free
            const float* gp = x + xbase + (size_t)(kc * 32 + srow) * 1024 + scol;
            float4 a0 = *(const float4*)gp;
            float4 a1 = *(const float4*)(gp + 4);
            *(float4*)&xf32[srow * 132 + scol] = a0;
            *(float4*)&xf32[srow * 132 + scol + 4] = a1;
            __syncthreads();                  // xf32 ready
            short8v hv, lv;
#pragma unroll
            for (int j2 = 0; j2 < 8; ++j2) {
                float v = xf32[(kq * 8 + j2) * 132 + ct];
                unsigned short h = f2bf(v);
                float hf = bf2f(h);
                unsigned short lo = f2bf(v - hf);
                hv[j2] = (short)h; lv[j2] = (short)lo;
                x2p = fmaf(v, v, x2p);
            }
            int pos = (kc * 4 + kq) ^ (ct & 31);          // XOR swizzle, 16B chunks
            *(short8v*)&xh[ct * 256 + pos * 8] = hv;
            *(short8v*)&xl[ct * 256 + pos * 8] = lv;
        }
        __syncthreads();
        float* x2sh = (float*)scr;            // [4][128]
        x2sh[kq * 128 + ct] = x2p;
        __syncthreads();
        if (tid < 128)
            x2tok = x2sh[tid] + x2sh[128 + tid] + x2sh[256 + tid] + x2sh[384 + tid];
        __syncthreads();                      // xh/xl complete; scr free
    }

    // ---- precomputed fragment offsets ----
    int aoffb[4], axor[4];
#pragma unroll
    for (int i = 0; i < 4; ++i) {
        int arow = th * 64 + i * 16 + lr;     // token row 0..127
        aoffb[i] = arow * 512;                // bytes (row = 256 shorts)
        axor[i] = arow & 31;
    }
    int boff_h[2], boff_l[2];
#pragma unroll
    for (int j = 0; j < 2; ++j) {
        int brow = cq * 32 + j * 16 + lr;     // row in 128-code tile, 128 B rows
        boff_h[j] = brow * 128 + ((quad ^ (brow & 7)) * 16);
        boff_l[j] = brow * 128 + (((4 + quad) ^ (brow & 7)) * 16);
    }
    const int drq = l >> 3;                   // DMA: row within 8-row group
    const int dch = (l & 7) ^ (drq & 7);      // source chunk (un-swizzle)
    const char* wpc = (const char*)wpack;

    // preload this wave's w2 values (keeps main-loop vmem = STAGE only)
    float w2v[16];
#pragma unroll
    for (int s2 = 0; s2 < 8; ++s2)
#pragma unroll
        for (int j = 0; j < 2; ++j)
            w2v[s2 * 2 + j] = w2g[s2 * 128 + cq * 32 + j * 16 + lr];

    float bval[16]; int bidx[16];
#pragma unroll
    for (int s2 = 0; s2 < 16; ++s2) { bval[s2] = FLT_MAX; bidx[s2] = 0; }
    const float4v zacc = {0.f, 0.f, 0.f, 0.f};

    // stage 16 KB tile g (strip g>>3, kc g&7) into wbuf[g&1]; 8 waves x 2 KB
    auto STAGE = [&](int g) {
        int sp = g >> 3, kcp = g & 7;
        char* dst = wbuf + (g & 1) * 16384 + wv * 2048;
#pragma unroll
        for (int u = 0; u < 2; ++u) {
            int code = sp * 128 + wv * 16 + u * 8 + drq;
            size_t src = ((size_t)code * 8 + kcp) * 128 + (size_t)dch * 16;
            gload16(wpc + src, dst + u * 1024);
        }
    };

    // ---- phase 2: 64 double-buffered steps (8 strips x 8 kc) ----
    STAGE(0);
#pragma unroll 1
    for (int s = 0; s < 8; ++s) {
        float4v acc[4][2];
#pragma unroll
        for (int i = 0; i < 4; ++i)
#pragma unroll
            for (int j = 0; j < 2; ++j) acc[i][j] = zacc;

#pragma unroll 1
        for (int kc = 0; kc < 8; ++kc) {
            const int g = s * 8 + kc;
            // (A) everyone done reading buf[(g-1)&1] -> safe to overwrite as buf[(g+1)&1]
            asm volatile("s_barrier" ::: "memory");
            if (g < 63) {
                STAGE(g + 1);
                // tile g's 2 DMAs retired (g+1's 2 stay in flight); then all waves sync
                asm volatile("s_waitcnt vmcnt(2)\n\ts_barrier" ::: "memory");
            } else {
                asm volatile("s_waitcnt vmcnt(0)\n\ts_barrier" ::: "memory");
            }
            const char* bufp = wbuf + (g & 1) * 16384;

            short8v ah[4], al[4], bh[2], bl[2];
#pragma unroll
            for (int i = 0; i < 4; ++i) {
                int pos = ((kc * 4 + quad) ^ axor[i]) * 16;
                ah[i] = *(const short8v*)(smem + aoffb[i] + pos);
                al[i] = *(const short8v*)(smem + 65536 + aoffb[i] + pos);
            }
#pragma unroll
            for (int j = 0; j < 2; ++j) {
                bh[j] = *(const short8v*)(bufp + boff_h[j]);
                bl[j] = *(const short8v*)(bufp + boff_l[j]);
            }
            __builtin_amdgcn_s_setprio(1);
#pragma unroll
            for (int i = 0; i < 4; ++i)
#pragma unroll
                for (int j = 0; j < 2; ++j) {
                    acc[i][j] = __builtin_amdgcn_mfma_f32_16x16x32_bf16(ah[i], bh[j], acc[i][j], 0, 0, 0);
                    acc[i][j] = __builtin_amdgcn_mfma_f32_16x16x32_bf16(ah[i], bl[j], acc[i][j], 0, 0, 0);
                    acc[i][j] = __builtin_amdgcn_mfma_f32_16x16x32_bf16(al[i], bh[j], acc[i][j], 0, 0, 0);
                }
            __builtin_amdgcn_s_setprio(0);
        }
        // fold strip into running per-token argmin
#pragma unroll
        for (int j = 0; j < 2; ++j) {
            int code = s * 128 + cq * 32 + j * 16 + lr;
            float w2c = w2v[s * 2 + j];
#pragma unroll
            for (int i = 0; i < 4; ++i)
#pragma unroll
                for (int rr = 0; rr < 4; ++rr) {
                    float sv = fmaf(-2.f, acc[i][j][rr], w2c);
                    int slot = i * 4 + rr;
                    if (sv < bval[slot]) { bval[slot] = sv; bidx[slot] = code; }
                }
        }
    }

    // ---- phase 3: argmin reduce, histogram, loss, gather/write ----
    __syncthreads();                          // all DMA + reads done; scr free
    float* bestv = (float*)scr;               // [8][64]
    int*   besti = (int*)(scr + 2048);        // [8][64]
    int*   idx_sh = (int*)(scr + 4096);       // [128]
#pragma unroll
    for (int slot = 0; slot < 16; ++slot) {
        float bv = bval[slot]; int bi = bidx[slot];
#pragma unroll
        for (int off = 1; off < 16; off <<= 1) {
            float ov = __shfl_xor(bv, off);
            int   oi = __shfl_xor(bi, off);
            if (ov < bv || (ov == bv && oi < bi)) { bv = ov; bi = oi; }
        }
        if (lr == 0) {
            int tloc = (slot >> 2) * 16 + quad * 4 + (slot & 3);   // 0..63 within half
            bestv[wv * 64 + tloc] = bv; besti[wv * 64 + tloc] = bi;
        }
    }
    __syncthreads();
    if (tid < 128) {
        int th2 = tid >> 6, tl = tid & 63;    // waves with th==th2: {th2, th2+2, th2+4, th2+6}
        float bv = bestv[th2 * 64 + tl]; int bi = besti[th2 * 64 + tl];
#pragma unroll
        for (int w = 1; w < 4; ++w) {
            float ov = bestv[(w * 2 + th2) * 64 + tl];
            int   oi = besti[(w * 2 + th2) * 64 + tl];
            if (ov < bv || (ov == bv && oi < bi)) { bv = ov; bi = oi; }
        }
        idx_sh[tid] = bi;
        atomicAdd(&hist[bi], 1);
        float lsum = bv + x2tok;              // |q-x|^2 = (w2 - 2 q.x) + x^2
#pragma unroll
        for (int off = 32; off > 0; off >>= 1) lsum += __shfl_down(lsum, off);
        if ((tid & 63) == 0) atomicAdd(lossp, lsum);
    }
    __syncthreads();
    {
        int t = tid & 127, cg = tid >> 7;
        int id = idx_sh[t];
        const float* erow = emb + (size_t)id * C_DIM;
        float* ob = out + xbase + t;
#pragma unroll
        for (int cb = 0; cb < 16; ++cb) {
            int c4 = cb * 16 + cg * 4;
            float4 q4 = *(const float4*)&erow[c4];
            ob[(size_t)(c4 + 0) * 1024] = q4.x;
            ob[(size_t)(c4 + 1) * 1024] = q4.y;
            ob[(size_t)(c4 + 2) * 1024] = q4.z;
            ob[(size_t)(c4 + 3) * 1024] = q4.w;
        }
    }
}

__global__ void finalize_kernel(const int* __restrict__ hist, const float* __restrict__ lossp,
                                float* __restrict__ out) {
    __shared__ float red[16];
    int tid = threadIdx.x;                  // 1024 threads
    float p = (float)hist[tid] * (1.f / 32768.f);
    float term = p * logf(p + 1e-6f);
#pragma unroll
    for (int off = 32; off > 0; off >>= 1) term += __shfl_down(term, off);
    if ((tid & 63) == 0) red[tid >> 6] = term;
    __syncthreads();
    if (tid == 0) {
        float s = 0.f;
#pragma unroll
        for (int i = 0; i < 16; ++i) s += red[i];
        out[8388608] = 0.25f * lossp[0] * (1.f / 8388608.f);   // quant_loss
        out[8388609] = expf(-s);                               // perplexity
    }
}

// ---- fallback path (round-1 kernel, known-correct) used only if ws too small ----
__global__ void w2_kernel(const float* __restrict__ w, float* __restrict__ w2) {
    int code = blockIdx.x * blockDim.x + threadIdx.x;
    const float4* r = (const float4*)(w + (size_t)code * C_DIM);
    float s = 0.f;
#pragma unroll 8
    for (int i = 0; i < C_DIM / 4; ++i) {
        float4 v = r[i];
        s += v.x * v.x + v.y * v.y + v.z * v.z + v.w * v.w;
    }
    w2[code] = s;
}

__launch_bounds__(256, 2)
__global__ void vq_main(const float* __restrict__ x, const float* __restrict__ emb,
                        float* __restrict__ out, int* __restrict__ hist,
                        float* __restrict__ lossp, const float* __restrict__ w2) {
    __shared__ float w_lds[8 * S_CODES];
    __shared__ float x_lds[C_DIM * 32];
    const int tid = threadIdx.x;
    const int l = tid & 63, wv = tid >> 6;
    const int t0 = blockIdx.x * 32;
    const int b = t0 >> 10, hw0 = t0 & 1023;
    const float* xbase = x + ((size_t)b * C_DIM << 10) + hw0;
    {
        int rl = tid & 7, r0 = tid >> 3;
        for (int rep = 0; rep < 8; ++rep) {
            int c = rep * 32 + r0;
            float4 v = *(const float4*)(xbase + ((size_t)c << 10) + rl * 4);
            *(float4*)&x_lds[c * 32 + rl * 4] = v;
        }
    }
    float4 pre[8];
#pragma unroll
    for (int m = 0; m < 8; ++m) {
        int fid = m * 256 + tid;
        int code = fid >> 1, kq = fid & 1;
        pre[m] = *(const float4*)(emb + (size_t)code * C_DIM + kq * 4);
    }
    float acc[8][16];
#pragma unroll
    for (int t = 0; t < 8; ++t)
#pragma unroll
        for (int j = 0; j < 16; ++j) acc[t][j] = 0.f;
    __syncthreads();
    for (int chunk = 0; chunk < 32; ++chunk) {
#pragma unroll
        for (int m = 0; m < 8; ++m) {
            int fid = m * 256 + tid;
            int code = fid >> 1, kq = fid & 1;
            float4 v = pre[m];
            w_lds[(kq * 4 + 0) * S_CODES + code] = v.x;
            w_lds[(kq * 4 + 1) * S_CODES + code] = v.y;
            w_lds[(kq * 4 + 2) * S_CODES + code] = v.z;
            w_lds[(kq * 4 + 3) * S_CODES + code] = v.w;
        }
        if (chunk + 1 < 32) {
            int k0n = (chunk + 1) * 8;
#pragma unroll
            for (int m = 0; m < 8; ++m) {
                int fid = m * 256 + tid;
                int code = fid >> 1, kq = fid & 1;
                pre[m] = *(const float4*)(emb + (size_t)code * C_DIM + k0n + kq * 4);
            }
        }
        __syncthreads();
        int k0 = chunk * 8;
#pragma unroll
        for (int kk = 0; kk < 8; ++kk) {
            int k = k0 + kk;
            float4 wq0 = *(const float4*)&w_lds[kk * S_CODES +   0 + l * 4];
            float4 wq1 = *(const float4*)&w_lds[kk * S_CODES + 256 + l * 4];
            float4 wq2 = *(const float4*)&w_lds[kk * S_CODES + 512 + l * 4];
            float4 wq3 = *(const float4*)&w_lds[kk * S_CODES + 768 + l * 4];
            float4 xa = *(const float4*)&x_lds[k * 32 + wv * 8];
            float4 xb = *(const float4*)&x_lds[k * 32 + wv * 8 + 4];
            float xs[8] = {xa.x, xa.y, xa.z, xa.w, xb.x, xb.y, xb.z, xb.w};
            float wvv[16] = {wq0.x, wq0.y, wq0.z, wq0.w, wq1.x, wq1.y, wq1.z, wq1.w,
                             wq2.x, wq2.y, wq2.z, wq2.w, wq3.x, wq3.y, wq3.z, wq3.w};
#pragma unroll
            for (int t = 0; t < 8; ++t) {
                float xv = xs[t];
#pragma unroll
                for (int j = 0; j < 16; ++j) acc[t][j] = fmaf(xv, wvv[j], acc[t][j]);
            }
        }
        __syncthreads();
    }
    float w2v[16];
#pragma unroll
    for (int m = 0; m < 4; ++m) {
        float4 v = *(const float4*)&w2[m * 256 + l * 4];
        w2v[m*4+0] = v.x; w2v[m*4+1] = v.y; w2v[m*4+2] = v.z; w2v[m*4+3] = v.w;
    }
    int* idx_sh = (int*)w_lds;
    float* red = (float*)(w_lds + 64);
#pragma unroll
    for (int t = 0; t < 8; ++t) {
        float bv = FLT_MAX; int bi = 0;
#pragma unroll
        for (int m = 0; m < 4; ++m)
#pragma unroll
            for (int j = 0; j < 4; ++j) {
                float s = w2v[m*4+j] - 2.f * acc[t][m*4+j];
                int c = m * 256 + l * 4 + j;
                if (s < bv) { bv = s; bi = c; }
            }
#pragma unroll
        for (int off = 32; off > 0; off >>= 1) {
            float ov = __shfl_xor(bv, off);
            int oi = __shfl_xor(bi, off);
            if (ov < bv || (ov == bv && oi < bi)) { bv = ov; bi = oi; }
        }
        if (l == 0) idx_sh[wv * 8 + t] = bi;
    }
    __syncthreads();
    if (tid < 32) atomicAdd(&hist[idx_sh[tid]], 1);
    float lsum = 0.f;
    for (int e = tid; e < C_DIM * 32; e += 256) {
        int t = e & 31, c = e >> 5;
        int id = idx_sh[t];
        float q = emb[(size_t)id * C_DIM + c];
        float xv = x_lds[c * 32 + t];
        float d = q - xv;
        lsum += d * d;
        out[((size_t)(b * C_DIM + c) << 10) + hw0 + t] = q;
    }
#pragma unroll
    for (int off = 32; off > 0; off >>= 1) lsum += __shfl_down(lsum, off);
    if (l == 0) red[wv] = lsum;
    __syncthreads();
    if (tid == 0) atomicAdd(lossp, red[0] + red[1] + red[2] + red[3]);
}

extern "C" void kernel_launch(void* const* d_in, const int* in_sizes, int n_in,
                              void* d_out, int out_size, void* d_ws, size_t ws_size,
                              hipStream_t stream) {
    const float* x   = (const float*)d_in[0];
    const float* emb = (const float*)d_in[1];
    float* out = (float*)d_out;
    char* ws = (char*)d_ws;
    int*   hist  = (int*)(ws + WS_HIST);
    float* lossp = (float*)(ws + WS_LOSS);
    float* w2    = (float*)(ws + WS_W2);

    if (ws_size >= WS_NEED) {
        unsigned short* wpack = (unsigned short*)(ws + WS_WPK);
        split_w<<<1024, 64, 0, stream>>>(emb, wpack, w2, hist, lossp);
        vq_fused4<<<256, 512, 0, stream>>>(x, emb, wpack, w2, out, hist, lossp);
    } else {
        hipMemsetAsync(d_ws, 0, 4608, stream);
        w2_kernel<<<4, 256, 0, stream>>>(emb, w2);
        vq_main<<<1024, 256, 0, stream>>>(x, emb, out, hist, lossp, w2);
    }
    finalize_kernel<<<1, 1024, 0, stream>>>(hist, lossp, out);
}

// Round 4
// 148.427 us; speedup vs baseline: 1.5673x; 1.0687x over previous
//
#include <hip/hip_runtime.h>
#include <hip/hip_bf16.h>
#include <cfloat>
#include <math.h>

#define N_TOK   32768
#define S_CODES 1024
#define C_DIM   256

typedef __attribute__((ext_vector_type(8))) short short8v;
typedef __attribute__((ext_vector_type(4))) float float4v;

// ---- workspace byte offsets ----
#define WS_HIST 0                       // 1024 int
#define WS_LOSS 4096                    // 1 float
#define WS_W2   4608                    // 1024 float
#define WS_WPK  16384                   // w_packed [1024 codes][8 kc][hi 64B | lo 64B] = 1 MB
#define WS_NEED ((size_t)(WS_WPK + 1048576))

__device__ __forceinline__ unsigned short f2bf(float f) {
    __hip_bfloat16 h = __float2bfloat16(f);
    return __builtin_bit_cast(unsigned short, h);
}
__device__ __forceinline__ float bf2f(unsigned short u) {
    return __bfloat162float(__builtin_bit_cast(__hip_bfloat16, u));
}
__device__ __forceinline__ void gload16(const void* g, void* l) {
    __builtin_amdgcn_global_load_lds((const __attribute__((address_space(1))) void*)g,
                                     (__attribute__((address_space(3))) void*)l, 16, 0, 0);
}

// ---- split w into packed hi/lo rows + squared norms; also zero hist/loss ----
__global__ void split_w(const float* __restrict__ w, unsigned short* __restrict__ wpack,
                        float* __restrict__ w2, int* __restrict__ hist,
                        float* __restrict__ lossp) {
    int c = blockIdx.x, l = threadIdx.x;       // 1024 blocks x 64 threads
    float4 v = ((const float4*)(w + (size_t)c * C_DIM))[l];   // k = l*4 .. +3
    float s = v.x*v.x + v.y*v.y + v.z*v.z + v.w*v.w;
    float vv[4] = {v.x, v.y, v.z, v.w};
    ushort4 h4, l4;
    unsigned short* hp = (unsigned short*)&h4;
    unsigned short* lp = (unsigned short*)&l4;
#pragma unroll
    for (int q = 0; q < 4; ++q) {
        hp[q] = f2bf(vv[q]);
        lp[q] = f2bf(vv[q] - bf2f(hp[q]));
    }
    size_t base = ((size_t)c * 8 + (l >> 3)) * 64;            // 64 shorts = 128 B per (c,kc)
    *(ushort4*)&wpack[base + (l & 7) * 4] = h4;               // hi half (bytes 0..63)
    *(ushort4*)&wpack[base + 32 + (l & 7) * 4] = l4;          // lo half (bytes 64..127)
#pragma unroll
    for (int off = 32; off > 0; off >>= 1) s += __shfl_down(s, off);
    if (l == 0) w2[c] = s;
    if (l == 32) hist[c] = 0;
    if (c == 0 && l == 33) *lossp = 0.f;
}

// ---- main: 128-token blocks, 8 waves (th = wv&1 token-half, cq = wv>>1 code-quarter).
//      x converted once to full-K LDS hi/lo (128 KB). W staged via global_load_lds in
//      16 KB tiles, double-buffered, counted vmcnt(2). SOFTWARE-PIPELINED fragments:
//      body g reads fragments for step g+1 into the idle frag set while step g's
//      MFMAs (whose operands were read one step earlier) run -> LDS pipe and MFMA
//      pipe overlap instead of alternating. LDS 163840, 1 block/CU, 8 waves. ----
__global__ void __launch_bounds__(512, 2)
vq_fused5(const float* __restrict__ x, const float* __restrict__ emb,
          const unsigned short* __restrict__ wpack, const float* __restrict__ w2g,
          float* __restrict__ out, int* __restrict__ hist, float* __restrict__ lossp) {
    __shared__ __align__(16) char smem[163840];
    // layout: xh [128 tok][256 k] bf16 (64 KB) | xl (64 KB) | W dbuf 2x16 KB
    unsigned short* xh = (unsigned short*)smem;
    unsigned short* xl = (unsigned short*)(smem + 65536);
    char* wbuf = smem + 131072;               // two 16 KB tile buffers
    char* scr  = smem + 131072;               // phase-1/3 scratch overlay (32 KB)

    const int tid = threadIdx.x;
    const int l = tid & 63, wv = tid >> 6;
    const int quad = l >> 4, lr = l & 15;
    const int th = wv & 1, cq = wv >> 1;      // token half / code quarter
    const int t0 = blockIdx.x * 128;
    const int b = t0 >> 10, hw0 = t0 & 1023;
    const size_t xbase = ((size_t)b << 18) + hw0;

    // ---- phase 1: stage + convert x (once) ----
    float x2tok = 0.f;                        // valid in tid<128 (token = tid)
    {
        float* xf32 = (float*)scr;            // [32 k][132] padded (16.9 KB < 32 KB)
        const int srow = tid >> 4, scol = (tid & 15) * 8;
        const int ct = tid & 127, kq = tid >> 7;
        float x2p = 0.f;
        for (int kc = 0; kc < 8; ++kc) {
            __syncthreads();                  // xf32 free
            const float* gp = x + xbase + (size_t)(kc * 32 + srow) * 1024 + scol;
            float4 a0 = *(const float4*)gp;
            float4 a1 = *(const float4*)(gp + 4);
            *(float4*)&xf32[srow * 132 + scol] = a0;
            *(float4*)&xf32[srow * 132 + scol + 4] = a1;
            __syncthreads();                  // xf32 ready
            short8v hv, lv;
#pragma unroll
            for (int j2 = 0; j2 < 8; ++j2) {
                float v = xf32[(kq * 8 + j2) * 132 + ct];
                unsigned short h = f2bf(v);
                float hf = bf2f(h);
                unsigned short lo = f2bf(v - hf);
                hv[j2] = (short)h; lv[j2] = (short)lo;
                x2p = fmaf(v, v, x2p);
            }
            int pos = (kc * 4 + kq) ^ (ct & 31);          // XOR swizzle, 16B chunks
            *(short8v*)&xh[ct * 256 + pos * 8] = hv;
            *(short8v*)&xl[ct * 256 + pos * 8] = lv;
        }
        __syncthreads();
        float* x2sh = (float*)scr;            // [4][128]
        x2sh[kq * 128 + ct] = x2p;
        __syncthreads();
        if (tid < 128)
            x2tok = x2sh[tid] + x2sh[128 + tid] + x2sh[256 + tid] + x2sh[384 + tid];
        __syncthreads();                      // xh/xl complete; scr free
    }

    // ---- precomputed fragment offsets ----
    int aoffb[4], axor[4];
#pragma unroll
    for (int i = 0; i < 4; ++i) {
        int arow = th * 64 + i * 16 + lr;     // token row 0..127
        aoffb[i] = arow * 512;                // bytes (row = 256 shorts)
        axor[i] = arow & 31;
    }
    int boff_h[2], boff_l[2];
#pragma unroll
    for (int j = 0; j < 2; ++j) {
        int brow = cq * 32 + j * 16 + lr;     // row in 128-code tile, 128 B rows
        boff_h[j] = brow * 128 + ((quad ^ (brow & 7)) * 16);
        boff_l[j] = brow * 128 + (((4 + quad) ^ (brow & 7)) * 16);
    }
    const int drq = l >> 3;                   // DMA: row within 8-row group
    const int dch = (l & 7) ^ (drq & 7);      // source chunk (un-swizzle)
    const char* wpc = (const char*)wpack;

    float bval[16]; int bidx[16];
#pragma unroll
    for (int s2 = 0; s2 < 16; ++s2) { bval[s2] = FLT_MAX; bidx[s2] = 0; }
    const float4v zacc = {0.f, 0.f, 0.f, 0.f};
    float4v acc[4][2];
#pragma unroll
    for (int i = 0; i < 4; ++i)
#pragma unroll
        for (int j = 0; j < 2; ++j) acc[i][j] = zacc;

    // stage 16 KB tile g (strip g>>3, kc g&7) into wbuf[g&1]; 8 waves x 2 KB
    auto STAGE = [&](int g) {
        int sp = g >> 3, kcp = g & 7;
        char* dst = wbuf + (g & 1) * 16384 + wv * 2048;
#pragma unroll
        for (int u = 0; u < 2; ++u) {
            int code = sp * 128 + wv * 16 + u * 8 + drq;
            size_t src = ((size_t)code * 8 + kcp) * 128 + (size_t)dch * 16;
            gload16(wpc + src, dst + u * 1024);
        }
    };

    struct Frags { short8v ah[4], al[4], bh[2], bl[2]; };
    Frags f0, f1;

    // read the 12 fragments for step g into f (A from immutable xh/xl, B from wbuf)
    auto READF = [&](Frags& f, int g) {
        const int kc = g & 7;
        const char* bufp = wbuf + (g & 1) * 16384;
#pragma unroll
        for (int i = 0; i < 4; ++i) {
            int pos = ((kc * 4 + quad) ^ axor[i]) * 16;
            f.ah[i] = *(const short8v*)(smem + aoffb[i] + pos);
            f.al[i] = *(const short8v*)(smem + 65536 + aoffb[i] + pos);
        }
#pragma unroll
        for (int j = 0; j < 2; ++j) {
            f.bh[j] = *(const short8v*)(bufp + boff_h[j]);
            f.bl[j] = *(const short8v*)(bufp + boff_l[j]);
        }
    };

    auto COMPUTE = [&](const Frags& f) {
        __builtin_amdgcn_s_setprio(1);
#pragma unroll
        for (int i = 0; i < 4; ++i)
#pragma unroll
            for (int j = 0; j < 2; ++j) {
                acc[i][j] = __builtin_amdgcn_mfma_f32_16x16x32_bf16(f.ah[i], f.bh[j], acc[i][j], 0, 0, 0);
                acc[i][j] = __builtin_amdgcn_mfma_f32_16x16x32_bf16(f.ah[i], f.bl[j], acc[i][j], 0, 0, 0);
                acc[i][j] = __builtin_amdgcn_mfma_f32_16x16x32_bf16(f.al[i], f.bh[j], acc[i][j], 0, 0, 0);
            }
        __builtin_amdgcn_s_setprio(0);
    };

    // fold strip s into running argmin, then reset acc (w2 loads are plain global
    // loads; FIFO vmcnt retirement means the next counted wait safely drains them)
    auto FOLD = [&](int s) {
#pragma unroll
        for (int j = 0; j < 2; ++j) {
            int code = s * 128 + cq * 32 + j * 16 + lr;
            float w2c = w2g[code];
#pragma unroll
            for (int i = 0; i < 4; ++i) {
#pragma unroll
                for (int rr = 0; rr < 4; ++rr) {
                    float sv = fmaf(-2.f, acc[i][j][rr], w2c);
                    int slot = i * 4 + rr;
                    if (sv < bval[slot]) { bval[slot] = sv; bidx[slot] = code; }
                }
                acc[i][j] = zacc;
            }
        }
    };

    // ---- phase 2: 64 steps, frag-pipelined (read g+1 while computing g) ----
    STAGE(0);
    STAGE(1);
    asm volatile("s_waitcnt vmcnt(2)" ::: "memory");   // tile 0 complete (own part)
    asm volatile("s_barrier" ::: "memory");            // all waves' tile 0 parts
    READF(f0, 0);

#pragma unroll 1
    for (int t = 0; t < 31; ++t) {
        const int g = 2 * t;
        // ---- body g: compute f0, prefetch f1 <- g+1, DMA tile g+2 ----
        asm volatile("s_barrier" ::: "memory");        // frags g read by all -> buf[g&1] free
        STAGE(g + 2);
        asm volatile("s_waitcnt vmcnt(2)\n\ts_barrier" ::: "memory");  // tile g+1 ready (all waves)
        READF(f1, g + 1);
        COMPUTE(f0);
        // ---- body g+1: compute f1, prefetch f0 <- g+2, DMA tile g+3 ----
        asm volatile("s_barrier" ::: "memory");
        STAGE(g + 3);
        asm volatile("s_waitcnt vmcnt(2)\n\ts_barrier" ::: "memory");
        READF(f0, g + 2);
        COMPUTE(f1);
        if ((t & 3) == 3) FOLD((2 * t + 1) >> 3);      // strip fold at g = 7,15,..,55
    }
    // ---- body 62: compute f0 (frags 62), prefetch f1 <- 63 ----
    asm volatile("s_barrier" ::: "memory");            // frags 62 read -> safe
    asm volatile("s_waitcnt vmcnt(0)\n\ts_barrier" ::: "memory");      // tile 63 ready
    READF(f1, 63);
    COMPUTE(f0);
    // ---- body 63: compute f1, final fold ----
    COMPUTE(f1);
    FOLD(7);

    // ---- phase 3: argmin reduce, histogram, loss, gather/write ----
    __syncthreads();                          // all DMA + reads done; scr free
    float* bestv = (float*)scr;               // [8][64]
    int*   besti = (int*)(scr + 2048);        // [8][64]
    int*   idx_sh = (int*)(scr + 4096);       // [128]
#pragma unroll
    for (int slot = 0; slot < 16; ++slot) {
        float bv = bval[slot]; int bi = bidx[slot];
#pragma unroll
        for (int off = 1; off < 16; off <<= 1) {
            float ov = __shfl_xor(bv, off);
            int   oi = __shfl_xor(bi, off);
            if (ov < bv || (ov == bv && oi < bi)) { bv = ov; bi = oi; }
        }
        if (lr == 0) {
            int tloc = (slot >> 2) * 16 + quad * 4 + (slot & 3);   // 0..63 within half
            bestv[wv * 64 + tloc] = bv; besti[wv * 64 + tloc] = bi;
        }
    }
    __syncthreads();
    if (tid < 128) {
        int th2 = tid >> 6, tl = tid & 63;    // waves with th==th2: {th2, th2+2, th2+4, th2+6}
        float bv = bestv[th2 * 64 + tl]; int bi = besti[th2 * 64 + tl];
#pragma unroll
        for (int w = 1; w < 4; ++w) {
            float ov = bestv[(w * 2 + th2) * 64 + tl];
            int   oi = besti[(w * 2 + th2) * 64 + tl];
            if (ov < bv || (ov == bv && oi < bi)) { bv = ov; bi = oi; }
        }
        idx_sh[tid] = bi;
        atomicAdd(&hist[bi], 1);
        float lsum = bv + x2tok;              // |q-x|^2 = (w2 - 2 q.x) + x^2
#pragma unroll
        for (int off = 32; off > 0; off >>= 1) lsum += __shfl_down(lsum, off);
        if ((tid & 63) == 0) atomicAdd(lossp, lsum);
    }
    __syncthreads();
    {
        int t = tid & 127, cg = tid >> 7;
        int id = idx_sh[t];
        const float* erow = emb + (size_t)id * C_DIM;
        float* ob = out + xbase + t;
#pragma unroll
        for (int cb = 0; cb < 16; ++cb) {
            int c4 = cb * 16 + cg * 4;
            float4 q4 = *(const float4*)&erow[c4];
            ob[(size_t)(c4 + 0) * 1024] = q4.x;
            ob[(size_t)(c4 + 1) * 1024] = q4.y;
            ob[(size_t)(c4 + 2) * 1024] = q4.z;
            ob[(size_t)(c4 + 3) * 1024] = q4.w;
        }
    }
}

__global__ void finalize_kernel(const int* __restrict__ hist, const float* __restrict__ lossp,
                                float* __restrict__ out) {
    __shared__ float red[16];
    int tid = threadIdx.x;                  // 1024 threads
    float p = (float)hist[tid] * (1.f / 32768.f);
    float term = p * logf(p + 1e-6f);
#pragma unroll
    for (int off = 32; off > 0; off >>= 1) term += __shfl_down(term, off);
    if ((tid & 63) == 0) red[tid >> 6] = term;
    __syncthreads();
    if (tid == 0) {
        float s = 0.f;
#pragma unroll
        for (int i = 0; i < 16; ++i) s += red[i];
        out[8388608] = 0.25f * lossp[0] * (1.f / 8388608.f);   // quant_loss
        out[8388609] = expf(-s);                               // perplexity
    }
}

// ---- fallback path (round-1 kernel, known-correct) used only if ws too small ----
__global__ void w2_kernel(const float* __restrict__ w, float* __restrict__ w2) {
    int code = blockIdx.x * blockDim.x + threadIdx.x;
    const float4* r = (const float4*)(w + (size_t)code * C_DIM);
    float s = 0.f;
#pragma unroll 8
    for (int i = 0; i < C_DIM / 4; ++i) {
        float4 v = r[i];
        s += v.x * v.x + v.y * v.y + v.z * v.z + v.w * v.w;
    }
    w2[code] = s;
}

__launch_bounds__(256, 2)
__global__ void vq_main(const float* __restrict__ x, const float* __restrict__ emb,
                        float* __restrict__ out, int* __restrict__ hist,
                        float* __restrict__ lossp, const float* __restrict__ w2) {
    __shared__ float w_lds[8 * S_CODES];
    __shared__ float x_lds[C_DIM * 32];
    const int tid = threadIdx.x;
    const int l = tid & 63, wv = tid >> 6;
    const int t0 = blockIdx.x * 32;
    const int b = t0 >> 10, hw0 = t0 & 1023;
    const float* xbase = x + ((size_t)b * C_DIM << 10) + hw0;
    {
        int rl = tid & 7, r0 = tid >> 3;
        for (int rep = 0; rep < 8; ++rep) {
            int c = rep * 32 + r0;
            float4 v = *(const float4*)(xbase + ((size_t)c << 10) + rl * 4);
            *(float4*)&x_lds[c * 32 + rl * 4] = v;
        }
    }
    float4 pre[8];
#pragma unroll
    for (int m = 0; m < 8; ++m) {
        int fid = m * 256 + tid;
        int code = fid >> 1, kq = fid & 1;
        pre[m] = *(const float4*)(emb + (size_t)code * C_DIM + kq * 4);
    }
    float acc[8][16];
#pragma unroll
    for (int t = 0; t < 8; ++t)
#pragma unroll
        for (int j = 0; j < 16; ++j) acc[t][j] = 0.f;
    __syncthreads();
    for (int chunk = 0; chunk < 32; ++chunk) {
#pragma unroll
        for (int m = 0; m < 8; ++m) {
            int fid = m * 256 + tid;
            int code = fid >> 1, kq = fid & 1;
            float4 v = pre[m];
            w_lds[(kq * 4 + 0) * S_CODES + code] = v.x;
            w_lds[(kq * 4 + 1) * S_CODES + code] = v.y;
            w_lds[(kq * 4 + 2) * S_CODES + code] = v.z;
            w_lds[(kq * 4 + 3) * S_CODES + code] = v.w;
        }
        if (chunk + 1 < 32) {
            int k0n = (chunk + 1) * 8;
#pragma unroll
            for (int m = 0; m < 8; ++m) {
                int fid = m * 256 + tid;
                int code = fid >> 1, kq = fid & 1;
                pre[m] = *(const float4*)(emb + (size_t)code * C_DIM + k0n + kq * 4);
            }
        }
        __syncthreads();
        int k0 = chunk * 8;
#pragma unroll
        for (int kk = 0; kk < 8; ++kk) {
            int k = k0 + kk;
            float4 wq0 = *(const float4*)&w_lds[kk * S_CODES +   0 + l * 4];
            float4 wq1 = *(const float4*)&w_lds[kk * S_CODES + 256 + l * 4];
            float4 wq2 = *(const float4*)&w_lds[kk * S_CODES + 512 + l * 4];
            float4 wq3 = *(const float4*)&w_lds[kk * S_CODES + 768 + l * 4];
            float4 xa = *(const float4*)&x_lds[k * 32 + wv * 8];
            float4 xb = *(const float4*)&x_lds[k * 32 + wv * 8 + 4];
            float xs[8] = {xa.x, xa.y, xa.z, xa.w, xb.x, xb.y, xb.z, xb.w};
            float wvv[16] = {wq0.x, wq0.y, wq0.z, wq0.w, wq1.x, wq1.y, wq1.z, wq1.w,
                             wq2.x, wq2.y, wq2.z, wq2.w, wq3.x, wq3.y, wq3.z, wq3.w};
#pragma unroll
            for (int t = 0; t < 8; ++t) {
                float xv = xs[t];
#pragma unroll
                for (int j = 0; j < 16; ++j) acc[t][j] = fmaf(xv, wvv[j], acc[t][j]);
            }
        }
        __syncthreads();
    }
    float w2v[16];
#pragma unroll
    for (int m = 0; m < 4; ++m) {
        float4 v = *(const float4*)&w2[m * 256 + l * 4];
        w2v[m*4+0] = v.x; w2v[m*4+1] = v.y; w2v[m*4+2] = v.z; w2v[m*4+3] = v.w;
    }
    int* idx_sh = (int*)w_lds;
    float* red = (float*)(w_lds + 64);
#pragma unroll
    for (int t = 0; t < 8; ++t) {
        float bv = FLT_MAX; int bi = 0;
#pragma unroll
        for (int m = 0; m < 4; ++m)
#pragma unroll
            for (int j = 0; j < 4; ++j) {
                float s = w2v[m*4+j] - 2.f * acc[t][m*4+j];
                int c = m * 256 + l * 4 + j;
                if (s < bv) { bv = s; bi = c; }
            }
#pragma unroll
        for (int off = 32; off > 0; off >>= 1) {
            float ov = __shfl_xor(bv, off);
            int oi = __shfl_xor(bi, off);
            if (ov < bv || (ov == bv && oi < bi)) { bv = ov; bi = oi; }
        }
        if (l == 0) idx_sh[wv * 8 + t] = bi;
    }
    __syncthreads();
    if (tid < 32) atomicAdd(&hist[idx_sh[tid]], 1);
    float lsum = 0.f;
    for (int e = tid; e < C_DIM * 32; e += 256) {
        int t = e & 31, c = e >> 5;
        int id = idx_sh[t];
        float q = emb[(size_t)id * C_DIM + c];
        float xv = x_lds[c * 32 + t];
        float d = q - xv;
        lsum += d * d;
        out[((size_t)(b * C_DIM + c) << 10) + hw0 + t] = q;
    }
#pragma unroll
    for (int off = 32; off > 0; off >>= 1) lsum += __shfl_down(lsum, off);
    if (l == 0) red[wv] = lsum;
    __syncthreads();
    if (tid == 0) atomicAdd(lossp, red[0] + red[1] + red[2] + red[3]);
}

extern "C" void kernel_launch(void* const* d_in, const int* in_sizes, int n_in,
                              void* d_out, int out_size, void* d_ws, size_t ws_size,
                              hipStream_t stream) {
    const float* x   = (const float*)d_in[0];
    const float* emb = (const float*)d_in[1];
    float* out = (float*)d_out;
    char* ws = (char*)d_ws;
    int*   hist  = (int*)(ws + WS_HIST);
    float* lossp = (float*)(ws + WS_LOSS);
    float* w2    = (float*)(ws + WS_W2);

    if (ws_size >= WS_NEED) {
        unsigned short* wpack = (unsigned short*)(ws + WS_WPK);
        split_w<<<1024, 64, 0, stream>>>(emb, wpack, w2, hist, lossp);
        vq_fused5<<<256, 512, 0, stream>>>(x, emb, wpack, w2, out, hist, lossp);
    } else {
        hipMemsetAsync(d_ws, 0, 4608, stream);
        w2_kernel<<<4, 256, 0, stream>>>(emb, w2);
        vq_main<<<1024, 256, 0, stream>>>(x, emb, out, hist, lossp, w2);
    }
    finalize_kernel<<<1, 1024, 0, stream>>>(hist, lossp, out);
}

// Round 5
// 146.679 us; speedup vs baseline: 1.5860x; 1.0119x over previous
//
#include <hip/hip_runtime.h>
#include <hip/hip_bf16.h>
#include <cfloat>
#include <math.h>

#define N_TOK   32768
#define S_CODES 1024
#define C_DIM   256

typedef __attribute__((ext_vector_type(8))) short short8v;
typedef __attribute__((ext_vector_type(4))) float float4v;

// ---- workspace byte offsets ----
#define WS_HIST 0                       // 1024 int
#define WS_LOSS 4096                    // 1 float
#define WS_W2   4608                    // 1024 float
#define WS_WPK  16384                   // w_packed [1024 codes][8 kc][hi 64B | lo 64B] = 1 MB
#define WS_NEED ((size_t)(WS_WPK + 1048576))

__device__ __forceinline__ unsigned short f2bf(float f) {
    __hip_bfloat16 h = __float2bfloat16(f);
    return __builtin_bit_cast(unsigned short, h);
}
__device__ __forceinline__ float bf2f(unsigned short u) {
    return __bfloat162float(__builtin_bit_cast(__hip_bfloat16, u));
}
__device__ __forceinline__ void gload16(const void* g, void* l) {
    __builtin_amdgcn_global_load_lds((const __attribute__((address_space(1))) void*)g,
                                     (__attribute__((address_space(3))) void*)l, 16, 0, 0);
}

// ---- split w into packed hi/lo rows + squared norms; also zero hist/loss ----
__global__ void split_w(const float* __restrict__ w, unsigned short* __restrict__ wpack,
                        float* __restrict__ w2, int* __restrict__ hist,
                        float* __restrict__ lossp) {
    int c = blockIdx.x, l = threadIdx.x;       // 1024 blocks x 64 threads
    float4 v = ((const float4*)(w + (size_t)c * C_DIM))[l];   // k = l*4 .. +3
    float s = v.x*v.x + v.y*v.y + v.z*v.z + v.w*v.w;
    float vv[4] = {v.x, v.y, v.z, v.w};
    ushort4 h4, l4;
    unsigned short* hp = (unsigned short*)&h4;
    unsigned short* lp = (unsigned short*)&l4;
#pragma unroll
    for (int q = 0; q < 4; ++q) {
        hp[q] = f2bf(vv[q]);
        lp[q] = f2bf(vv[q] - bf2f(hp[q]));
    }
    size_t base = ((size_t)c * 8 + (l >> 3)) * 64;            // 64 shorts = 128 B per (c,kc)
    *(ushort4*)&wpack[base + (l & 7) * 4] = h4;               // hi half (bytes 0..63)
    *(ushort4*)&wpack[base + 32 + (l & 7) * 4] = l4;          // lo half (bytes 64..127)
#pragma unroll
    for (int off = 32; off > 0; off >>= 1) s += __shfl_down(s, off);
    if (l == 0) w2[c] = s;
    if (l == 32) hist[c] = 0;
    if (c == 0 && l == 33) *lossp = 0.f;
}

// ---- main: 128-token blocks, 8 waves (th = wv&1 token-half, cq = wv>>1 code-quarter).
//      x converted once, DIRECTLY from coalesced global reads (no LDS bounce, no
//      barriers) into full-K LDS hi/lo (128 KB); first two W tiles' DMA issued
//      BEFORE phase 1 so it hides under the conversion. W staged via global_load_lds
//      16 KB tiles, double-buffered, counted vmcnt(2). Fragment software pipeline
//      enforced with sched_barrier(0) pins (rule #18: MFMAs otherwise hoist across
//      asm "memory" barriers and collapse the pipeline -> r4's VGPR=104). ----
__global__ void __launch_bounds__(512, 2)
vq_fused6(const float* __restrict__ x, const float* __restrict__ emb,
          const unsigned short* __restrict__ wpack, const float* __restrict__ w2g,
          float* __restrict__ out, int* __restrict__ hist, float* __restrict__ lossp) {
    __shared__ __align__(16) char smem[163840];
    // layout: xh [128 tok][256 k] bf16 (64 KB) | xl (64 KB) | W dbuf 2x16 KB
    unsigned short* xh = (unsigned short*)smem;
    unsigned short* xl = (unsigned short*)(smem + 65536);
    char* wbuf = smem + 131072;               // two 16 KB tile buffers
    char* scr  = smem + 131072;               // phase-3 scratch overlay (32 KB)

    const int tid = threadIdx.x;
    const int l = tid & 63, wv = tid >> 6;
    const int quad = l >> 4, lr = l & 15;
    const int th = wv & 1, cq = wv >> 1;      // token half / code quarter
    const int t0 = blockIdx.x * 128;
    const int b = t0 >> 10, hw0 = t0 & 1023;
    const size_t xbase = ((size_t)b << 18) + hw0;

    const int drq = l >> 3;                   // DMA: row within 8-row group
    const int dch = (l & 7) ^ (drq & 7);      // source chunk (un-swizzle)
    const char* wpc = (const char*)wpack;

    // stage 16 KB tile g (strip g>>3, kc g&7) into wbuf[g&1]; 8 waves x 2 KB
    auto STAGE = [&](int g) {
        int sp = g >> 3, kcp = g & 7;
        char* dst = wbuf + (g & 1) * 16384 + wv * 2048;
#pragma unroll
        for (int u = 0; u < 2; ++u) {
            int code = sp * 128 + wv * 16 + u * 8 + drq;
            size_t src = ((size_t)code * 8 + kcp) * 128 + (size_t)dch * 16;
            gload16(wpc + src, dst + u * 1024);
        }
    };

    // W tiles 0,1 DMA in flight during all of phase 1
    STAGE(0);
    STAGE(1);

    // ---- phase 1: convert x, barrier-free (coalesced scalar loads; the old
    //      xf32 LDS bounce was an identity transpose costing 16 full drains) ----
    float x2p = 0.f;                          // partial |x|^2: token ct, k-quarter kq
    {
        const int ct = tid & 127, kq = tid >> 7;
        const float* gp0 = x + xbase + (size_t)(kq * 8) * 1024 + ct;
#pragma unroll 2
        for (int kc = 0; kc < 8; ++kc) {
            const float* gp = gp0 + (size_t)(kc * 32) * 1024;
            float v8[8];
#pragma unroll
            for (int j2 = 0; j2 < 8; ++j2) v8[j2] = gp[(size_t)j2 * 1024];
            short8v hv, lv;
#pragma unroll
            for (int j2 = 0; j2 < 8; ++j2) {
                float v = v8[j2];
                unsigned short h = f2bf(v);
                float hf = bf2f(h);
                unsigned short lo = f2bf(v - hf);
                hv[j2] = (short)h; lv[j2] = (short)lo;
                x2p = fmaf(v, v, x2p);
            }
            int pos = (kc * 4 + kq) ^ (ct & 31);          // XOR swizzle, 16B chunks
            *(short8v*)&xh[ct * 256 + pos * 8] = hv;
            *(short8v*)&xl[ct * 256 + pos * 8] = lv;
        }
    }
    __syncthreads();   // xh/xl ready; full drain also retires tile-0/1 DMA

    // ---- precomputed fragment offsets ----
    int aoffb[4], axor[4];
#pragma unroll
    for (int i = 0; i < 4; ++i) {
        int arow = th * 64 + i * 16 + lr;     // token row 0..127
        aoffb[i] = arow * 512;                // bytes (row = 256 shorts)
        axor[i] = arow & 31;
    }
    int boff_h[2], boff_l[2];
#pragma unroll
    for (int j = 0; j < 2; ++j) {
        int brow = cq * 32 + j * 16 + lr;     // row in 128-code tile, 128 B rows
        boff_h[j] = brow * 128 + ((quad ^ (brow & 7)) * 16);
        boff_l[j] = brow * 128 + (((4 + quad) ^ (brow & 7)) * 16);
    }

    float bval[16]; int bidx[16];
#pragma unroll
    for (int s2 = 0; s2 < 16; ++s2) { bval[s2] = FLT_MAX; bidx[s2] = 0; }
    const float4v zacc = {0.f, 0.f, 0.f, 0.f};
    float4v acc[4][2];
#pragma unroll
    for (int i = 0; i < 4; ++i)
#pragma unroll
        for (int j = 0; j < 2; ++j) acc[i][j] = zacc;

    struct Frags { short8v ah[4], al[4], bh[2], bl[2]; };
    Frags f0, f1;

    // read the 12 fragments for step g into f (A from immutable xh/xl, B from wbuf)
    auto READF = [&](Frags& f, int g) {
        const int kc = g & 7;
        const char* bufp = wbuf + (g & 1) * 16384;
#pragma unroll
        for (int i = 0; i < 4; ++i) {
            int pos = ((kc * 4 + quad) ^ axor[i]) * 16;
            f.ah[i] = *(const short8v*)(smem + aoffb[i] + pos);
            f.al[i] = *(const short8v*)(smem + 65536 + aoffb[i] + pos);
        }
#pragma unroll
        for (int j = 0; j < 2; ++j) {
            f.bh[j] = *(const short8v*)(bufp + boff_h[j]);
            f.bl[j] = *(const short8v*)(bufp + boff_l[j]);
        }
    };

    auto COMPUTE = [&](const Frags& f) {
        __builtin_amdgcn_s_setprio(1);
#pragma unroll
        for (int i = 0; i < 4; ++i)
#pragma unroll
            for (int j = 0; j < 2; ++j) {
                acc[i][j] = __builtin_amdgcn_mfma_f32_16x16x32_bf16(f.ah[i], f.bh[j], acc[i][j], 0, 0, 0);
                acc[i][j] = __builtin_amdgcn_mfma_f32_16x16x32_bf16(f.ah[i], f.bl[j], acc[i][j], 0, 0, 0);
                acc[i][j] = __builtin_amdgcn_mfma_f32_16x16x32_bf16(f.al[i], f.bh[j], acc[i][j], 0, 0, 0);
            }
        __builtin_amdgcn_s_setprio(0);
    };

    // fold strip s into running argmin, then reset acc (w2 global loads enter the
    // vmcnt FIFO; the next counted wait retires them along with the older DMAs)
    auto FOLD = [&](int s) {
#pragma unroll
        for (int j = 0; j < 2; ++j) {
            int code = s * 128 + cq * 32 + j * 16 + lr;
            float w2c = w2g[code];
#pragma unroll
            for (int i = 0; i < 4; ++i) {
#pragma unroll
                for (int rr = 0; rr < 4; ++rr) {
                    float sv = fmaf(-2.f, acc[i][j][rr], w2c);
                    int slot = i * 4 + rr;
                    if (sv < bval[slot]) { bval[slot] = sv; bidx[slot] = code; }
                }
                acc[i][j] = zacc;
            }
        }
    };

#define SBAR0() __builtin_amdgcn_sched_barrier(0)

    // ---- phase 2: 64 steps, frag-pipelined (read g+1 while computing g) ----
    READF(f0, 0);

#pragma unroll 1
    for (int t = 0; t < 31; ++t) {
        const int g = 2 * t;
        // ---- body g: prefetch f1 <- g+1, compute f0, DMA tile g+2 ----
        asm volatile("s_barrier" ::: "memory");        // frags g read by all -> buf[g&1] free
        STAGE(g + 2);
        asm volatile("s_waitcnt vmcnt(2)\n\ts_barrier" ::: "memory");  // tile g+1 ready (all waves)
        READF(f1, g + 1);
        SBAR0();                                       // pin: MFMA may not hoist above
        COMPUTE(f0);
        SBAR0();
        // ---- body g+1: prefetch f0 <- g+2, compute f1, DMA tile g+3 ----
        asm volatile("s_barrier" ::: "memory");
        STAGE(g + 3);
        asm volatile("s_waitcnt vmcnt(2)\n\ts_barrier" ::: "memory");
        READF(f0, g + 2);
        SBAR0();
        COMPUTE(f1);
        SBAR0();
        if ((t & 3) == 3) FOLD((2 * t + 1) >> 3);      // strip fold at g = 7,15,..,55
    }
    // ---- body 62: compute f0 (frags 62), prefetch f1 <- 63 ----
    asm volatile("s_barrier" ::: "memory");            // frags 62 read -> safe
    asm volatile("s_waitcnt vmcnt(0)\n\ts_barrier" ::: "memory");      // tile 63 ready
    READF(f1, 63);
    SBAR0();
    COMPUTE(f0);
    SBAR0();
    // ---- body 63: compute f1, final fold ----
    COMPUTE(f1);
    FOLD(7);

    // ---- phase 3: x2 reduce, argmin reduce, histogram, loss, gather/write ----
    __syncthreads();                          // all DMA + reads done; scr free
    float* bestv = (float*)scr;               // [8][64]
    int*   besti = (int*)(scr + 2048);        // [8][64]
    int*   idx_sh = (int*)(scr + 4096);       // [128]
    float* x2sh  = (float*)(scr + 8192);      // [4][128]
    x2sh[tid] = x2p;                          // tid = kq*128 + ct
#pragma unroll
    for (int slot = 0; slot < 16; ++slot) {
        float bv = bval[slot]; int bi = bidx[slot];
#pragma unroll
        for (int off = 1; off < 16; off <<= 1) {
            float ov = __shfl_xor(bv, off);
            int   oi = __shfl_xor(bi, off);
            if (ov < bv || (ov == bv && oi < bi)) { bv = ov; bi = oi; }
        }
        if (lr == 0) {
            int tloc = (slot >> 2) * 16 + quad * 4 + (slot & 3);   // 0..63 within half
            bestv[wv * 64 + tloc] = bv; besti[wv * 64 + tloc] = bi;
        }
    }
    __syncthreads();
    if (tid < 128) {
        float x2tok = x2sh[tid] + x2sh[128 + tid] + x2sh[256 + tid] + x2sh[384 + tid];
        int th2 = tid >> 6, tl = tid & 63;    // waves with th==th2: {th2, th2+2, th2+4, th2+6}
        float bv = bestv[th2 * 64 + tl]; int bi = besti[th2 * 64 + tl];
#pragma unroll
        for (int w = 1; w < 4; ++w) {
            float ov = bestv[(w * 2 + th2) * 64 + tl];
            int   oi = besti[(w * 2 + th2) * 64 + tl];
            if (ov < bv || (ov == bv && oi < bi)) { bv = ov; bi = oi; }
        }
        idx_sh[tid] = bi;
        atomicAdd(&hist[bi], 1);
        float lsum = bv + x2tok;              // |q-x|^2 = (w2 - 2 q.x) + x^2
#pragma unroll
        for (int off = 32; off > 0; off >>= 1) lsum += __shfl_down(lsum, off);
        if ((tid & 63) == 0) atomicAdd(lossp, lsum);
    }
    __syncthreads();
    {
        int t = tid & 127, cg = tid >> 7;
        int id = idx_sh[t];
        const float* erow = emb + (size_t)id * C_DIM;
        float* ob = out + xbase + t;
#pragma unroll
        for (int cb = 0; cb < 16; ++cb) {
            int c4 = cb * 16 + cg * 4;
            float4 q4 = *(const float4*)&erow[c4];
            ob[(size_t)(c4 + 0) * 1024] = q4.x;
            ob[(size_t)(c4 + 1) * 1024] = q4.y;
            ob[(size_t)(c4 + 2) * 1024] = q4.z;
            ob[(size_t)(c4 + 3) * 1024] = q4.w;
        }
    }
#undef SBAR0
}

__global__ void finalize_kernel(const int* __restrict__ hist, const float* __restrict__ lossp,
                                float* __restrict__ out) {
    __shared__ float red[16];
    int tid = threadIdx.x;                  // 1024 threads
    float p = (float)hist[tid] * (1.f / 32768.f);
    float term = p * logf(p + 1e-6f);
#pragma unroll
    for (int off = 32; off > 0; off >>= 1) term += __shfl_down(term, off);
    if ((tid & 63) == 0) red[tid >> 6] = term;
    __syncthreads();
    if (tid == 0) {
        float s = 0.f;
#pragma unroll
        for (int i = 0; i < 16; ++i) s += red[i];
        out[8388608] = 0.25f * lossp[0] * (1.f / 8388608.f);   // quant_loss
        out[8388609] = expf(-s);                               // perplexity
    }
}

// ---- fallback path (round-1 kernel, known-correct) used only if ws too small ----
__global__ void w2_kernel(const float* __restrict__ w, float* __restrict__ w2) {
    int code = blockIdx.x * blockDim.x + threadIdx.x;
    const float4* r = (const float4*)(w + (size_t)code * C_DIM);
    float s = 0.f;
#pragma unroll 8
    for (int i = 0; i < C_DIM / 4; ++i) {
        float4 v = r[i];
        s += v.x * v.x + v.y * v.y + v.z * v.z + v.w * v.w;
    }
    w2[code] = s;
}

__launch_bounds__(256, 2)
__global__ void vq_main(const float* __restrict__ x, const float* __restrict__ emb,
                        float* __restrict__ out, int* __restrict__ hist,
                        float* __restrict__ lossp, const float* __restrict__ w2) {
    __shared__ float w_lds[8 * S_CODES];
    __shared__ float x_lds[C_DIM * 32];
    const int tid = threadIdx.x;
    const int l = tid & 63, wv = tid >> 6;
    const int t0 = blockIdx.x * 32;
    const int b = t0 >> 10, hw0 = t0 & 1023;
    const float* xbase = x + ((size_t)b * C_DIM << 10) + hw0;
    {
        int rl = tid & 7, r0 = tid >> 3;
        for (int rep = 0; rep < 8; ++rep) {
            int c = rep * 32 + r0;
            float4 v = *(const float4*)(xbase + ((size_t)c << 10) + rl * 4);
            *(float4*)&x_lds[c * 32 + rl * 4] = v;
        }
    }
    float4 pre[8];
#pragma unroll
    for (int m = 0; m < 8; ++m) {
        int fid = m * 256 + tid;
        int code = fid >> 1, kq = fid & 1;
        pre[m] = *(const float4*)(emb + (size_t)code * C_DIM + kq * 4);
    }
    float acc[8][16];
#pragma unroll
    for (int t = 0; t < 8; ++t)
#pragma unroll
        for (int j = 0; j < 16; ++j) acc[t][j] = 0.f;
    __syncthreads();
    for (int chunk = 0; chunk < 32; ++chunk) {
#pragma unroll
        for (int m = 0; m < 8; ++m) {
            int fid = m * 256 + tid;
            int code = fid >> 1, kq = fid & 1;
            float4 v = pre[m];
            w_lds[(kq * 4 + 0) * S_CODES + code] = v.x;
            w_lds[(kq * 4 + 1) * S_CODES + code] = v.y;
            w_lds[(kq * 4 + 2) * S_CODES + code] = v.z;
            w_lds[(kq * 4 + 3) * S_CODES + code] = v.w;
        }
        if (chunk + 1 < 32) {
            int k0n = (chunk + 1) * 8;
#pragma unroll
            for (int m = 0; m < 8; ++m) {
                int fid = m * 256 + tid;
                int code = fid >> 1, kq = fid & 1;
                pre[m] = *(const float4*)(emb + (size_t)code * C_DIM + k0n + kq * 4);
            }
        }
        __syncthreads();
        int k0 = chunk * 8;
#pragma unroll
        for (int kk = 0; kk < 8; ++kk) {
            int k = k0 + kk;
            float4 wq0 = *(const float4*)&w_lds[kk * S_CODES +   0 + l * 4];
            float4 wq1 = *(const float4*)&w_lds[kk * S_CODES + 256 + l * 4];
            float4 wq2 = *(const float4*)&w_lds[kk * S_CODES + 512 + l * 4];
            float4 wq3 = *(const float4*)&w_lds[kk * S_CODES + 768 + l * 4];
            float4 xa = *(const float4*)&x_lds[k * 32 + wv * 8];
            float4 xb = *(const float4*)&x_lds[k * 32 + wv * 8 + 4];
            float xs[8] = {xa.x, xa.y, xa.z, xa.w, xb.x, xb.y, xb.z, xb.w};
            float wvv[16] = {wq0.x, wq0.y, wq0.z, wq0.w, wq1.x, wq1.y, wq1.z, wq1.w,
                             wq2.x, wq2.y, wq2.z, wq2.w, wq3.x, wq3.y, wq3.z, wq3.w};
#pragma unroll
            for (int t = 0; t < 8; ++t) {
                float xv = xs[t];
#pragma unroll
                for (int j = 0; j < 16; ++j) acc[t][j] = fmaf(xv, wvv[j], acc[t][j]);
            }
        }
        __syncthreads();
    }
    float w2v[16];
#pragma unroll
    for (int m = 0; m < 4; ++m) {
        float4 v = *(const float4*)&w2[m * 256 + l * 4];
        w2v[m*4+0] = v.x; w2v[m*4+1] = v.y; w2v[m*4+2] = v.z; w2v[m*4+3] = v.w;
    }
    int* idx_sh = (int*)w_lds;
    float* red = (float*)(w_lds + 64);
#pragma unroll
    for (int t = 0; t < 8; ++t) {
        float bv = FLT_MAX; int bi = 0;
#pragma unroll
        for (int m = 0; m < 4; ++m)
#pragma unroll
            for (int j = 0; j < 4; ++j) {
                float s = w2v[m*4+j] - 2.f * acc[t][m*4+j];
                int c = m * 256 + l * 4 + j;
                if (s < bv) { bv = s; bi = c; }
            }
#pragma unroll
        for (int off = 32; off > 0; off >>= 1) {
            float ov = __shfl_xor(bv, off);
            int oi = __shfl_xor(bi, off);
            if (ov < bv || (ov == bv && oi < bi)) { bv = ov; bi = oi; }
        }
        if (l == 0) idx_sh[wv * 8 + t] = bi;
    }
    __syncthreads();
    if (tid < 32) atomicAdd(&hist[idx_sh[tid]], 1);
    float lsum = 0.f;
    for (int e = tid; e < C_DIM * 32; e += 256) {
        int t = e & 31, c = e >> 5;
        int id = idx_sh[t];
        float q = emb[(size_t)id * C_DIM + c];
        float xv = x_lds[c * 32 + t];
        float d = q - xv;
        lsum += d * d;
        out[((size_t)(b * C_DIM + c) << 10) + hw0 + t] = q;
    }
#pragma unroll
    for (int off = 32; off > 0; off >>= 1) lsum += __shfl_down(lsum, off);
    if (l == 0) red[wv] = lsum;
    __syncthreads();
    if (tid == 0) atomicAdd(lossp, red[0] + red[1] + red[2] + red[3]);
}

extern "C" void kernel_launch(void* const* d_in, const int* in_sizes, int n_in,
                              void* d_out, int out_size, void* d_ws, size_t ws_size,
                              hipStream_t stream) {
    const float* x   = (const float*)d_in[0];
    const float* emb = (const float*)d_in[1];
    float* out = (float*)d_out;
    char* ws = (char*)d_ws;
    int*   hist  = (int*)(ws + WS_HIST);
    float* lossp = (float*)(ws + WS_LOSS);
    float* w2    = (float*)(ws + WS_W2);

    if (ws_size >= WS_NEED) {
        unsigned short* wpack = (unsigned short*)(ws + WS_WPK);
        split_w<<<1024, 64, 0, stream>>>(emb, wpack, w2, hist, lossp);
        vq_fused6<<<256, 512, 0, stream>>>(x, emb, wpack, w2, out, hist, lossp);
    } else {
        hipMemsetAsync(d_ws, 0, 4608, stream);
        w2_kernel<<<4, 256, 0, stream>>>(emb, w2);
        vq_main<<<1024, 256, 0, stream>>>(x, emb, out, hist, lossp, w2);
    }
    finalize_kernel<<<1, 1024, 0, stream>>>(hist, lossp, out);
}